// Round 6
// baseline (1138.610 us; speedup 1.0000x reference)
//
#include <hip/hip_runtime.h>
#include <hip/hip_bf16.h>

#define DH 128          // feature dim (D_IN == H == 128)
#define SCB 1024        // scan elements per block

typedef __attribute__((ext_vector_type(8))) short short8_t;
typedef __attribute__((ext_vector_type(4))) float f32x4;

static __device__ __forceinline__ short f2bf(float f) {
    union { float f; unsigned u; } v; v.f = f;
    unsigned r = v.u + 0x7fffu + ((v.u >> 16) & 1u);   // RNE
    return (short)(r >> 16);
}

static __device__ __forceinline__ short8_t cvt8(const float* p) {
    float4 a0 = *(const float4*)p;
    float4 a1 = *(const float4*)(p + 4);
    short8_t t;
    t[0] = f2bf(a0.x); t[1] = f2bf(a0.y); t[2] = f2bf(a0.z); t[3] = f2bf(a0.w);
    t[4] = f2bf(a1.x); t[5] = f2bf(a1.y); t[6] = f2bf(a1.z); t[7] = f2bf(a1.w);
    return t;
}

// ---------------- degree histogram ----------------
__global__ void deg_count_k(const int* __restrict__ ei, int E, unsigned* __restrict__ cnt) {
    int e = blockIdx.x * 256 + threadIdx.x;
    if (e < E) atomicAdd(&cnt[ei[E + e]], 1u);
}

// ---------------- 3-phase grid-parallel exclusive scan ----------------
__global__ __launch_bounds__(256) void scan1_k(const unsigned* __restrict__ cnt, int N,
                                               int* __restrict__ offs, unsigned* __restrict__ bsum) {
    __shared__ unsigned s[256];
    int t = threadIdx.x;
    int i0 = blockIdx.x * SCB + t * 4;
    unsigned v0 = (i0 + 0 < N) ? cnt[i0 + 0] : 0u;
    unsigned v1 = (i0 + 1 < N) ? cnt[i0 + 1] : 0u;
    unsigned v2 = (i0 + 2 < N) ? cnt[i0 + 2] : 0u;
    unsigned v3 = (i0 + 3 < N) ? cnt[i0 + 3] : 0u;
    unsigned ts = v0 + v1 + v2 + v3;
    s[t] = ts;
    __syncthreads();
    for (int off = 1; off < 256; off <<= 1) {
        unsigned u = (t >= off) ? s[t - off] : 0u;
        __syncthreads();
        s[t] += u;
        __syncthreads();
    }
    unsigned ex = s[t] - ts;
    if (i0 + 0 < N) offs[i0 + 0] = (int)ex;
    if (i0 + 1 < N) offs[i0 + 1] = (int)(ex + v0);
    if (i0 + 2 < N) offs[i0 + 2] = (int)(ex + v0 + v1);
    if (i0 + 3 < N) offs[i0 + 3] = (int)(ex + v0 + v1 + v2);
    if (t == 255) bsum[blockIdx.x] = s[255];
}

__global__ __launch_bounds__(1024) void scan2_k(unsigned* __restrict__ bsum, int B) {
    __shared__ unsigned s[1024];
    int t = threadIdx.x;
    unsigned v = (t < B) ? bsum[t] : 0u;
    s[t] = v;
    __syncthreads();
    for (int off = 1; off < 1024; off <<= 1) {
        unsigned u = (t >= off) ? s[t - off] : 0u;
        __syncthreads();
        s[t] += u;
        __syncthreads();
    }
    if (t < B) bsum[t] = s[t] - v;
    if (t == 0) bsum[B] = s[1023];
}

__global__ void scan3_k(int* __restrict__ offs, int* __restrict__ cur,
                        float* __restrict__ dinv, const unsigned* __restrict__ cnt,
                        const unsigned* __restrict__ bsum, int N, int B) {
    int i = blockIdx.x * 256 + threadIdx.x;
    if (i < N) {
        int v = offs[i] + (int)bsum[i >> 10];
        offs[i] = v;
        cur[i] = v;
        dinv[i] = rsqrtf((float)cnt[i] + 1.0f);
    }
    if (i == 0) offs[N] = (int)bsum[B];
}

// ---------------- CSR fill: edges bucketed by dst ----------------
__global__ void fill_k(const int* __restrict__ ei, int E,
                       int* __restrict__ cur, int* __restrict__ csr_src) {
    int e = blockIdx.x * 256 + threadIdx.x;
    if (e < E) {
        int d = ei[E + e];
        int pos = atomicAdd(&cur[d], 1);
        csr_src[pos] = ei[e];
    }
}

// ---------------- weight prep ----------------
__global__ void f2bf6_k(const float* __restrict__ s0, const float* __restrict__ s1,
                        const float* __restrict__ s2, const float* __restrict__ s3,
                        const float* __restrict__ s4, const float* __restrict__ s5,
                        short* __restrict__ dst, int WN) {
    int i = blockIdx.x * 256 + threadIdx.x;
    if (i >= 6 * WN) return;
    int b = i / WN, r = i - b * WN;
    const float* srcs[6] = {s0, s1, s2, s3, s4, s5};
    dst[i] = f2bf(srcs[b][r]);
}

__global__ void transpose_bf2_k(const float* __restrict__ sa, const float* __restrict__ sb,
                                short* __restrict__ da, short* __restrict__ db) {
    int i = blockIdx.x * 256 + threadIdx.x;   // 2*16384
    int m = i >> 14;
    int j = i & 16383;
    int c = j >> 7, k = j & 127;
    const float* s = m ? sb : sa;
    short* d = m ? db : da;
    d[j] = f2bf(s[k * DH + c]);
}

// ---------------- MFMA GEMM with LDS-staged weights ----------------
// C[N,128] = A[N,128] @ Wt^T, Wt bf16 [c][k]. 512 thr / 8 waves,
// 256 rows per stripe, weights staged once per block in lane-contiguous layout:
// chunk(t,ks,lane) = Wt[t*16 + (lane&15)][ks*32 + (lane>>4)*8 .. +8]
__global__ __launch_bounds__(512) void gemm_mfma_k(const float* __restrict__ A,
                                                   const short* __restrict__ Wt,
                                                   float* __restrict__ C, int N, int nstripes) {
    __shared__ short wlds[2048 * 8];   // 32 KB
    int tid = threadIdx.x;
#pragma unroll
    for (int i = 0; i < 4; i++) {
        int c = tid + i * 512;                 // t*256 + ks*64 + ln
        int t = c >> 8, ks = (c >> 6) & 3, ln = c & 63;
        int grow = t * 16 + (ln & 15);
        int gk = ks * 32 + (ln >> 4) * 8;
        *(short8_t*)(wlds + (size_t)c * 8) = *(const short8_t*)(Wt + (size_t)grow * DH + gk);
    }
    __syncthreads();

    int wave = tid >> 6, lane = tid & 63;
    int lr = lane & 15, kg = lane >> 4;

    for (int st = blockIdx.x; st < nstripes; st += gridDim.x) {
        int row0 = st * 256 + wave * 32;
        int ar0 = min(row0 + lr, N - 1);
        int ar1 = min(row0 + 16 + lr, N - 1);
        const float* a0p = A + (size_t)ar0 * DH;
        const float* a1p = A + (size_t)ar1 * DH;
        short8_t af[2][4];
#pragma unroll
        for (int ks = 0; ks < 4; ks++) {
            af[0][ks] = cvt8(a0p + ks * 32 + kg * 8);
            af[1][ks] = cvt8(a1p + ks * 32 + kg * 8);
        }
#pragma unroll
        for (int t = 0; t < 8; t++) {
            short8_t b[4];
#pragma unroll
            for (int ks = 0; ks < 4; ks++)
                b[ks] = *(const short8_t*)(wlds + (size_t)(t * 256 + ks * 64 + lane) * 8);
            f32x4 acc0 = {0.f, 0.f, 0.f, 0.f};
            f32x4 acc1 = {0.f, 0.f, 0.f, 0.f};
#pragma unroll
            for (int ks = 0; ks < 4; ks++) {
                acc0 = __builtin_amdgcn_mfma_f32_16x16x32_bf16(af[0][ks], b[ks], acc0, 0, 0, 0);
                acc1 = __builtin_amdgcn_mfma_f32_16x16x32_bf16(af[1][ks], b[ks], acc1, 0, 0, 0);
            }
            int col = t * 16 + lr;
#pragma unroll
            for (int j = 0; j < 4; j++) {
                int g0 = row0 + kg * 4 + j;
                int g1 = row0 + 16 + kg * 4 + j;
                if (g0 < N) C[(size_t)g0 * DH + col] = acc0[j];
                if (g1 < N) C[(size_t)g1 * DH + col] = acc1[j];
            }
        }
    }
}

// ---------------- gather (unchanged) ----------------
__global__ __launch_bounds__(256) void gather_k(const int* __restrict__ csr_src,
                                                const int* __restrict__ offs,
                                                const float* __restrict__ dinv,
                                                const float* __restrict__ xw,
                                                const float* __restrict__ bias,
                                                float* __restrict__ dest, int N) {
    int wid = blockIdx.x * 4 + (threadIdx.x >> 6);
    if (wid >= N) return;
    int lane = threadIdx.x & 63;
    int j = offs[wid];
    int end = offs[wid + 1];
    float dd = dinv[wid];
    const float2* xw2 = (const float2*)xw;
    float ax = 0.f, ay = 0.f;

    if (j < end) {
        int s = csr_src[j];
        float dv = dinv[s];
        for (; j + 1 < end; ++j) {
            int sn = csr_src[j + 1];
            float dvn = dinv[sn];
            float2 v = xw2[(size_t)s * 64 + lane];
            float nrm = dd * dv;
            ax = fmaf(v.x, nrm, ax);
            ay = fmaf(v.y, nrm, ay);
            s = sn; dv = dvn;
        }
        float2 v = xw2[(size_t)s * 64 + lane];
        float nrm = dd * dv;
        ax = fmaf(v.x, nrm, ax);
        ay = fmaf(v.y, nrm, ay);
    }

    float2 xv = xw2[(size_t)wid * 64 + lane];
    float2 b2 = ((const float2*)bias)[lane];
    float sl = dd * dd;
    float ox = fmaxf(fmaf(xv.x, sl, ax) + b2.x, 0.f);
    float oy = fmaxf(fmaf(xv.y, sl, ay) + b2.y, 0.f);
    float2 o; o.x = ox; o.y = oy;
    ((float2*)dest)[(size_t)wid * 64 + lane] = o;
}

// ---------------- fused MFMA GRU cell, LDS-staged weights ----------------
// 512 thr / 8 waves. Block handles 64 output cols (cg = blockIdx&1) so both
// weight matrices' slices fit LDS (96 KB). Grid-strides over 256-row stripes.
// LDS chunk layout: idx = mat*3072 + g*1024 + t*256 + ks*64 + lane, each chunk
// = the short8 B-fragment lane needs for (gate g, col-tile t, k-slice ks).
__global__ __launch_bounds__(512, 2) void gru_mfma_k(const float* __restrict__ X,
                                                     const float* __restrict__ Hs,
                                                     const short* __restrict__ wih,
                                                     const short* __restrict__ whh,
                                                     const float* __restrict__ bih,
                                                     const float* __restrict__ bhh,
                                                     float* __restrict__ out, int N, int nstripes) {
    __shared__ short wlds[6144 * 8];   // 96 KB
    int tid = threadIdx.x;
    int cg = blockIdx.x & 1;
#pragma unroll
    for (int i = 0; i < 12; i++) {
        int c = tid + i * 512;
        int mat = (c >= 3072) ? 1 : 0;
        int r = c - mat * 3072;
        int g = r >> 10;
        int r2 = r & 1023;
        int t = r2 >> 8, ks = (r2 >> 6) & 3, ln = r2 & 63;
        const short* W = mat ? whh : wih;
        int grow = g * DH + cg * 64 + t * 16 + (ln & 15);
        int gk = ks * 32 + (ln >> 4) * 8;
        *(short8_t*)(wlds + (size_t)c * 8) = *(const short8_t*)(W + (size_t)grow * DH + gk);
    }
    __syncthreads();

    int wave = tid >> 6, lane = tid & 63;
    int lr = lane & 15, kg = lane >> 4;
    int nb = gridDim.x >> 1;

    for (int st = blockIdx.x >> 1; st < nstripes; st += nb) {
        int row0 = st * 256 + wave * 32;
        int ar0 = min(row0 + lr, N - 1);
        int ar1 = min(row0 + 16 + lr, N - 1);
        const float* x0 = X + (size_t)ar0 * DH;
        const float* x1 = X + (size_t)ar1 * DH;
        const float* h0 = Hs + (size_t)ar0 * DH;
        const float* h1p = Hs + (size_t)ar1 * DH;

        short8_t ax[2][4], ah[2][4];
#pragma unroll
        for (int ks = 0; ks < 4; ks++) {
            int ko = ks * 32 + kg * 8;
            ax[0][ks] = cvt8(x0 + ko);
            ax[1][ks] = cvt8(x1 + ko);
            ah[0][ks] = cvt8(h0 + ko);
            ah[1][ks] = cvt8(h1p + ko);
        }

#pragma unroll
        for (int t = 0; t < 4; t++) {
            int tb = t * 256 + lane;
            short8_t bi[4], bh[4];
            f32x4 aR0 = {0,0,0,0}, aR1 = {0,0,0,0};
            f32x4 aZ0 = {0,0,0,0}, aZ1 = {0,0,0,0};
            f32x4 aI0 = {0,0,0,0}, aI1 = {0,0,0,0};
            f32x4 aH0 = {0,0,0,0}, aH1 = {0,0,0,0};

            // R gate (g=0): acc = X@Wr + H@Ur chained into same acc
#pragma unroll
            for (int ks = 0; ks < 4; ks++) {
                bi[ks] = *(const short8_t*)(wlds + (size_t)(tb + ks * 64) * 8);
                bh[ks] = *(const short8_t*)(wlds + (size_t)(3072 + tb + ks * 64) * 8);
            }
#pragma unroll
            for (int ks = 0; ks < 4; ks++) {
                aR0 = __builtin_amdgcn_mfma_f32_16x16x32_bf16(ax[0][ks], bi[ks], aR0, 0, 0, 0);
                aR1 = __builtin_amdgcn_mfma_f32_16x16x32_bf16(ax[1][ks], bi[ks], aR1, 0, 0, 0);
                aR0 = __builtin_amdgcn_mfma_f32_16x16x32_bf16(ah[0][ks], bh[ks], aR0, 0, 0, 0);
                aR1 = __builtin_amdgcn_mfma_f32_16x16x32_bf16(ah[1][ks], bh[ks], aR1, 0, 0, 0);
            }
            // Z gate (g=1)
#pragma unroll
            for (int ks = 0; ks < 4; ks++) {
                bi[ks] = *(const short8_t*)(wlds + (size_t)(1024 + tb + ks * 64) * 8);
                bh[ks] = *(const short8_t*)(wlds + (size_t)(3072 + 1024 + tb + ks * 64) * 8);
            }
#pragma unroll
            for (int ks = 0; ks < 4; ks++) {
                aZ0 = __builtin_amdgcn_mfma_f32_16x16x32_bf16(ax[0][ks], bi[ks], aZ0, 0, 0, 0);
                aZ1 = __builtin_amdgcn_mfma_f32_16x16x32_bf16(ax[1][ks], bi[ks], aZ1, 0, 0, 0);
                aZ0 = __builtin_amdgcn_mfma_f32_16x16x32_bf16(ah[0][ks], bh[ks], aZ0, 0, 0, 0);
                aZ1 = __builtin_amdgcn_mfma_f32_16x16x32_bf16(ah[1][ks], bh[ks], aZ1, 0, 0, 0);
            }
            // N gate (g=2): i_n and h_n kept separate (r * h_n term)
#pragma unroll
            for (int ks = 0; ks < 4; ks++) {
                bi[ks] = *(const short8_t*)(wlds + (size_t)(2048 + tb + ks * 64) * 8);
                bh[ks] = *(const short8_t*)(wlds + (size_t)(3072 + 2048 + tb + ks * 64) * 8);
            }
#pragma unroll
            for (int ks = 0; ks < 4; ks++) {
                aI0 = __builtin_amdgcn_mfma_f32_16x16x32_bf16(ax[0][ks], bi[ks], aI0, 0, 0, 0);
                aI1 = __builtin_amdgcn_mfma_f32_16x16x32_bf16(ax[1][ks], bi[ks], aI1, 0, 0, 0);
                aH0 = __builtin_amdgcn_mfma_f32_16x16x32_bf16(ah[0][ks], bh[ks], aH0, 0, 0, 0);
                aH1 = __builtin_amdgcn_mfma_f32_16x16x32_bf16(ah[1][ks], bh[ks], aH1, 0, 0, 0);
            }

            // epilogue for this 16-col tile
            int gcol = cg * 64 + t * 16 + lr;
            float br = bih[gcol], bz = bih[DH + gcol], bn = bih[2 * DH + gcol];
            float cr = bhh[gcol], cz = bhh[DH + gcol], cn = bhh[2 * DH + gcol];
#pragma unroll
            for (int rt = 0; rt < 2; rt++) {
                f32x4 R = rt ? aR1 : aR0;
                f32x4 Z = rt ? aZ1 : aZ0;
                f32x4 I = rt ? aI1 : aI0;
                f32x4 Hn = rt ? aH1 : aH0;
#pragma unroll
                for (int j = 0; j < 4; j++) {
                    int grow = row0 + rt * 16 + kg * 4 + j;
                    if (grow < N) {
                        float hv = Hs[(size_t)grow * DH + gcol];
                        float r = 1.f / (1.f + __expf(-(R[j] + br + cr)));
                        float z = 1.f / (1.f + __expf(-(Z[j] + bz + cz)));
                        float n = tanhf(I[j] + bn + r * (Hn[j] + cn));
                        out[(size_t)grow * DH + gcol] = (1.f - z) * n + z * hv;
                    }
                }
            }
        }
    }
}

extern "C" void kernel_launch(void* const* d_in, const int* in_sizes, int n_in,
                              void* d_out, int out_size, void* d_ws, size_t ws_size,
                              hipStream_t stream) {
    const float* x    = (const float*)d_in[0];
    const int*   ei   = (const int*)d_in[1];
    const float* h1   = (const float*)d_in[2];
    const float* h2   = (const float*)d_in[3];
    const float* h3   = (const float*)d_in[4];
    const float* g1w  = (const float*)d_in[5];
    const float* g1b  = (const float*)d_in[6];
    const float* g2w  = (const float*)d_in[7];
    const float* g2b  = (const float*)d_in[8];
    const float* wih1 = (const float*)d_in[9];
    const float* whh1 = (const float*)d_in[10];
    const float* bih1 = (const float*)d_in[11];
    const float* bhh1 = (const float*)d_in[12];
    const float* wih2 = (const float*)d_in[13];
    const float* whh2 = (const float*)d_in[14];
    const float* bih2 = (const float*)d_in[15];
    const float* bhh2 = (const float*)d_in[16];
    const float* wih3 = (const float*)d_in[17];
    const float* whh3 = (const float*)d_in[18];
    const float* bih3 = (const float*)d_in[19];
    const float* bhh3 = (const float*)d_in[20];

    int N = in_sizes[0] / DH;
    int E = in_sizes[1] / 2;
    int B = (N + SCB - 1) / SCB;
    int nstripes = (N + 255) / 256;

    char* wsp = (char*)d_ws;
    auto alloc = [&](size_t bytes) -> char* {
        char* p = wsp;
        wsp += (bytes + 63) & ~(size_t)63;
        return p;
    };
    unsigned* cnt = (unsigned*)alloc((size_t)N * 4);
    int* offs     = (int*)alloc(((size_t)N + 1) * 4);
    int* cur      = (int*)alloc((size_t)N * 4);
    float* dinv   = (float*)alloc((size_t)N * 4);
    unsigned* bsum= (unsigned*)alloc(((size_t)B + 1) * 4);
    int* csr_src  = (int*)alloc((size_t)E * 4);
    float* xw     = (float*)alloc((size_t)N * DH * 4);
    float* x2     = (float*)alloc((size_t)N * DH * 4);
    short* w1t    = (short*)alloc((size_t)DH * DH * 2);
    short* w2t    = (short*)alloc((size_t)DH * DH * 2);
    const int WN = 3 * DH * DH;      // 49152
    short* wbAll  = (short*)alloc((size_t)6 * WN * 2);
    short* wb[6];
    for (int i = 0; i < 6; i++) wb[i] = wbAll + (size_t)i * WN;

    float* out  = (float*)d_out;
    float* h1n  = out;
    float* h2n  = out + (size_t)N * DH;
    float* h3n  = out + 2 * (size_t)N * DH;

    // ---- weight prep (bf16) ----
    f2bf6_k<<<(6 * WN + 255) / 256, 256, 0, stream>>>(wih1, whh1, wih2, whh2, wih3, whh3, wbAll, WN);
    transpose_bf2_k<<<(2 * DH * DH + 255) / 256, 256, 0, stream>>>(g1w, g2w, w1t, w2t);

    // ---- CSR build (per call; deterministic) ----
    hipMemsetAsync(cnt, 0, (size_t)N * 4, stream);
    deg_count_k<<<(E + 255) / 256, 256, 0, stream>>>(ei, E, cnt);
    scan1_k<<<B, 256, 0, stream>>>(cnt, N, offs, bsum);
    scan2_k<<<1, 1024, 0, stream>>>(bsum, B);
    scan3_k<<<(N + 255) / 256, 256, 0, stream>>>(offs, cur, dinv, cnt, bsum, N, B);
    fill_k<<<(E + 255) / 256, 256, 0, stream>>>(ei, E, cur, csr_src);

    int gblocks = (N + 3) / 4;

    // ---- GCN layer 1 ----
    gemm_mfma_k<<<nstripes, 512, 0, stream>>>(x, w1t, xw, N, nstripes);
    gather_k<<<gblocks, 256, 0, stream>>>(csr_src, offs, dinv, xw, g1b, x2, N);

    // ---- GCN layer 2 ----
    gemm_mfma_k<<<nstripes, 512, 0, stream>>>(x2, w2t, xw, N, nstripes);
    gather_k<<<gblocks, 256, 0, stream>>>(csr_src, offs, dinv, xw, g2b, x2, N);

    // ---- GRU chain ----
    gru_mfma_k<<<256, 512, 0, stream>>>(x2,  h1, wb[0], wb[1], bih1, bhh1, h1n, N, nstripes);
    gru_mfma_k<<<256, 512, 0, stream>>>(h1n, h2, wb[2], wb[3], bih2, bhh2, h2n, N, nstripes);
    gru_mfma_k<<<256, 512, 0, stream>>>(h2n, h3, wb[4], wb[5], bih3, bhh3, h3n, N, nstripes);
}

// Round 7
// 1037.268 us; speedup vs baseline: 1.0977x; 1.0977x over previous
//
#include <hip/hip_runtime.h>
#include <hip/hip_bf16.h>

#define DH 128          // feature dim (D_IN == H == 128)
#define SCB 1024        // scan elements per block

typedef __attribute__((ext_vector_type(8))) short short8_t;
typedef __attribute__((ext_vector_type(4))) float f32x4;

static __device__ __forceinline__ short f2bf(float f) {
    union { float f; unsigned u; } v; v.f = f;
    unsigned r = v.u + 0x7fffu + ((v.u >> 16) & 1u);   // RNE
    return (short)(r >> 16);
}

static __device__ __forceinline__ short8_t cvt8(const float* p) {
    float4 a0 = *(const float4*)p;
    float4 a1 = *(const float4*)(p + 4);
    short8_t t;
    t[0] = f2bf(a0.x); t[1] = f2bf(a0.y); t[2] = f2bf(a0.z); t[3] = f2bf(a0.w);
    t[4] = f2bf(a1.x); t[5] = f2bf(a1.y); t[6] = f2bf(a1.z); t[7] = f2bf(a1.w);
    return t;
}

// ---------------- degree histogram ----------------
__global__ void deg_count_k(const int* __restrict__ ei, int E, unsigned* __restrict__ cnt) {
    int e = blockIdx.x * 256 + threadIdx.x;
    if (e < E) atomicAdd(&cnt[ei[E + e]], 1u);
}

// ---------------- 3-phase grid-parallel exclusive scan ----------------
__global__ __launch_bounds__(256) void scan1_k(const unsigned* __restrict__ cnt, int N,
                                               int* __restrict__ offs, unsigned* __restrict__ bsum) {
    __shared__ unsigned s[256];
    int t = threadIdx.x;
    int i0 = blockIdx.x * SCB + t * 4;
    unsigned v0 = (i0 + 0 < N) ? cnt[i0 + 0] : 0u;
    unsigned v1 = (i0 + 1 < N) ? cnt[i0 + 1] : 0u;
    unsigned v2 = (i0 + 2 < N) ? cnt[i0 + 2] : 0u;
    unsigned v3 = (i0 + 3 < N) ? cnt[i0 + 3] : 0u;
    unsigned ts = v0 + v1 + v2 + v3;
    s[t] = ts;
    __syncthreads();
    for (int off = 1; off < 256; off <<= 1) {
        unsigned u = (t >= off) ? s[t - off] : 0u;
        __syncthreads();
        s[t] += u;
        __syncthreads();
    }
    unsigned ex = s[t] - ts;
    if (i0 + 0 < N) offs[i0 + 0] = (int)ex;
    if (i0 + 1 < N) offs[i0 + 1] = (int)(ex + v0);
    if (i0 + 2 < N) offs[i0 + 2] = (int)(ex + v0 + v1);
    if (i0 + 3 < N) offs[i0 + 3] = (int)(ex + v0 + v1 + v2);
    if (t == 255) bsum[blockIdx.x] = s[255];
}

__global__ __launch_bounds__(1024) void scan2_k(unsigned* __restrict__ bsum, int B) {
    __shared__ unsigned s[1024];
    int t = threadIdx.x;
    unsigned v = (t < B) ? bsum[t] : 0u;
    s[t] = v;
    __syncthreads();
    for (int off = 1; off < 1024; off <<= 1) {
        unsigned u = (t >= off) ? s[t - off] : 0u;
        __syncthreads();
        s[t] += u;
        __syncthreads();
    }
    if (t < B) bsum[t] = s[t] - v;
    if (t == 0) bsum[B] = s[1023];
}

__global__ void scan3_k(int* __restrict__ offs, int* __restrict__ cur,
                        float* __restrict__ dinv, const unsigned* __restrict__ cnt,
                        const unsigned* __restrict__ bsum, int N, int B) {
    int i = blockIdx.x * 256 + threadIdx.x;
    if (i < N) {
        int v = offs[i] + (int)bsum[i >> 10];
        offs[i] = v;
        cur[i] = v;
        dinv[i] = rsqrtf((float)cnt[i] + 1.0f);
    }
    if (i == 0) offs[N] = (int)bsum[B];
}

// ---------------- CSR fill: edges bucketed by dst ----------------
__global__ void fill_k(const int* __restrict__ ei, int E,
                       int* __restrict__ cur, int* __restrict__ csr_src) {
    int e = blockIdx.x * 256 + threadIdx.x;
    if (e < E) {
        int d = ei[E + e];
        int pos = atomicAdd(&cur[d], 1);
        csr_src[pos] = ei[e];
    }
}

// ---------------- weight prep ----------------
__global__ void f2bf6_k(const float* __restrict__ s0, const float* __restrict__ s1,
                        const float* __restrict__ s2, const float* __restrict__ s3,
                        const float* __restrict__ s4, const float* __restrict__ s5,
                        short* __restrict__ dst, int WN) {
    int i = blockIdx.x * 256 + threadIdx.x;
    if (i >= 6 * WN) return;
    int b = i / WN, r = i - b * WN;
    const float* srcs[6] = {s0, s1, s2, s3, s4, s5};
    dst[i] = f2bf(srcs[b][r]);
}

__global__ void transpose_bf2_k(const float* __restrict__ sa, const float* __restrict__ sb,
                                short* __restrict__ da, short* __restrict__ db) {
    int i = blockIdx.x * 256 + threadIdx.x;   // 2*16384
    int m = i >> 14;
    int j = i & 16383;
    int c = j >> 7, k = j & 127;
    const float* s = m ? sb : sa;
    short* d = m ? db : da;
    d[j] = f2bf(s[k * DH + c]);
}

// ================= MFMA GEMM, register-streamed weights, depth-2 prefetch ===========
// C[N,128] = A[N,128] @ Wt^T, Wt bf16 [c][k]. 256 thr / 4 waves, 128-row stripes
// via atomic work queue. Weight tile t prefetched 2 groups ahead (slot t%3).
__global__ __launch_bounds__(256, 4) void gemm_mfma_k(const float* __restrict__ A,
                                                      const short* __restrict__ Wt,
                                                      float* __restrict__ C, int N,
                                                      int nstripes, int* __restrict__ q) {
    int tid = threadIdx.x;
    int wave = tid >> 6, lane = tid & 63;
    int lr = lane & 15, kg = lane >> 4;
    __shared__ int s_st;

    for (;;) {
        if (tid == 0) s_st = atomicAdd(q, 1);
        __syncthreads();
        int st = s_st;
        __syncthreads();
        if (st >= nstripes) break;

        int row0 = st * 128 + wave * 32;
        int ar0 = min(row0 + lr, N - 1);
        int ar1 = min(row0 + 16 + lr, N - 1);
        const float* a0p = A + (size_t)ar0 * DH;
        const float* a1p = A + (size_t)ar1 * DH;
        short8_t af[2][4];
#pragma unroll
        for (int ks = 0; ks < 4; ks++) {
            af[0][ks] = cvt8(a0p + ks * 32 + kg * 8);
            af[1][ks] = cvt8(a1p + ks * 32 + kg * 8);
        }

        short8_t bt[3][4];
#define GLOADW(slot, t) { \
        const short* wp = Wt + (size_t)((t) * 16 + lr) * DH + kg * 8; \
        bt[slot][0] = *(const short8_t*)(wp); \
        bt[slot][1] = *(const short8_t*)(wp + 32); \
        bt[slot][2] = *(const short8_t*)(wp + 64); \
        bt[slot][3] = *(const short8_t*)(wp + 96); }

        GLOADW(0, 0)
        GLOADW(1, 1)
#pragma unroll
        for (int t = 0; t < 8; t++) {
            if (t < 6) GLOADW((t + 2) % 3, t + 2)
            f32x4 acc0 = {0.f, 0.f, 0.f, 0.f};
            f32x4 acc1 = {0.f, 0.f, 0.f, 0.f};
#pragma unroll
            for (int ks = 0; ks < 4; ks++) {
                acc0 = __builtin_amdgcn_mfma_f32_16x16x32_bf16(af[0][ks], bt[t % 3][ks], acc0, 0, 0, 0);
                acc1 = __builtin_amdgcn_mfma_f32_16x16x32_bf16(af[1][ks], bt[t % 3][ks], acc1, 0, 0, 0);
            }
            int col = t * 16 + lr;
#pragma unroll
            for (int j = 0; j < 4; j++) {
                int g0 = row0 + kg * 4 + j;
                int g1 = row0 + 16 + kg * 4 + j;
                if (g0 < N) C[(size_t)g0 * DH + col] = acc0[j];
                if (g1 < N) C[(size_t)g1 * DH + col] = acc1[j];
            }
        }
#undef GLOADW
    }
}

// ---------------- gather (unchanged) ----------------
__global__ __launch_bounds__(256) void gather_k(const int* __restrict__ csr_src,
                                                const int* __restrict__ offs,
                                                const float* __restrict__ dinv,
                                                const float* __restrict__ xw,
                                                const float* __restrict__ bias,
                                                float* __restrict__ dest, int N) {
    int wid = blockIdx.x * 4 + (threadIdx.x >> 6);
    if (wid >= N) return;
    int lane = threadIdx.x & 63;
    int j = offs[wid];
    int end = offs[wid + 1];
    float dd = dinv[wid];
    const float2* xw2 = (const float2*)xw;
    float ax = 0.f, ay = 0.f;

    if (j < end) {
        int s = csr_src[j];
        float dv = dinv[s];
        for (; j + 1 < end; ++j) {
            int sn = csr_src[j + 1];
            float dvn = dinv[sn];
            float2 v = xw2[(size_t)s * 64 + lane];
            float nrm = dd * dv;
            ax = fmaf(v.x, nrm, ax);
            ay = fmaf(v.y, nrm, ay);
            s = sn; dv = dvn;
        }
        float2 v = xw2[(size_t)s * 64 + lane];
        float nrm = dd * dv;
        ax = fmaf(v.x, nrm, ax);
        ay = fmaf(v.y, nrm, ay);
    }

    float2 xv = xw2[(size_t)wid * 64 + lane];
    float2 b2 = ((const float2*)bias)[lane];
    float sl = dd * dd;
    float ox = fmaxf(fmaf(xv.x, sl, ax) + b2.x, 0.f);
    float oy = fmaxf(fmaf(xv.y, sl, ay) + b2.y, 0.f);
    float2 o; o.x = ox; o.y = oy;
    ((float2*)dest)[(size_t)wid * 64 + lane] = o;
}

// ================= fused MFMA GRU cell, depth-2 weight prefetch ====================
// wih/whh bf16 [384][128]. 256 thr / 4 waves, 128-row stripes via work queue.
// Groups (t=col-tile, gate R/Z/N); slot == gate (3 named buffer pairs);
// group g prefetched during group g-2 -> ~2 group-durations of L2 latency cover.
__global__ __launch_bounds__(256, 2) void gru_mfma_k(const float* __restrict__ X,
                                                     const float* __restrict__ Hs,
                                                     const short* __restrict__ wih,
                                                     const short* __restrict__ whh,
                                                     const float* __restrict__ bih,
                                                     const float* __restrict__ bhh,
                                                     float* __restrict__ out, int N,
                                                     int nstripes, int* __restrict__ q) {
    int tid = threadIdx.x;
    int wave = tid >> 6, lane = tid & 63;
    int lr = lane & 15, kg = lane >> 4;
    __shared__ int s_st;

    for (;;) {
        if (tid == 0) s_st = atomicAdd(q, 1);
        __syncthreads();
        int st = s_st;
        __syncthreads();
        if (st >= nstripes) break;

        int row0 = st * 128 + wave * 32;
        int ar0 = min(row0 + lr, N - 1);
        int ar1 = min(row0 + 16 + lr, N - 1);
        const float* x0 = X + (size_t)ar0 * DH;
        const float* x1 = X + (size_t)ar1 * DH;
        const float* h0 = Hs + (size_t)ar0 * DH;
        const float* h1p = Hs + (size_t)ar1 * DH;

        short8_t ax[2][4], ah[2][4];
#pragma unroll
        for (int ks = 0; ks < 4; ks++) {
            int ko = ks * 32 + kg * 8;
            ax[0][ks] = cvt8(x0 + ko);
            ax[1][ks] = cvt8(x1 + ko);
            ah[0][ks] = cvt8(h0 + ko);
            ah[1][ks] = cvt8(h1p + ko);
        }

        short8_t biR[4], bhR[4], biZ[4], bhZ[4], biN[4], bhN[4];
#define WLOAD(bi_, bh_, g, t) { \
        const short* wi_ = wih + (size_t)((g) * DH + (t) * 16 + lr) * DH + kg * 8; \
        const short* wh_ = whh + (size_t)((g) * DH + (t) * 16 + lr) * DH + kg * 8; \
        bi_[0] = *(const short8_t*)(wi_);      bh_[0] = *(const short8_t*)(wh_); \
        bi_[1] = *(const short8_t*)(wi_ + 32); bh_[1] = *(const short8_t*)(wh_ + 32); \
        bi_[2] = *(const short8_t*)(wi_ + 64); bh_[2] = *(const short8_t*)(wh_ + 64); \
        bi_[3] = *(const short8_t*)(wi_ + 96); bh_[3] = *(const short8_t*)(wh_ + 96); }

        WLOAD(biR, bhR, 0, 0)           // R(0)
        WLOAD(biZ, bhZ, 1, 0)           // Z(0)
#pragma unroll
        for (int t = 0; t < 8; t++) {
            f32x4 aR0 = {0,0,0,0}, aR1 = {0,0,0,0};
            f32x4 aZ0 = {0,0,0,0}, aZ1 = {0,0,0,0};
            f32x4 aI0 = {0,0,0,0}, aI1 = {0,0,0,0};
            f32x4 aH0 = {0,0,0,0}, aH1 = {0,0,0,0};

            WLOAD(biN, bhN, 2, t)       // prefetch N(t)
#pragma unroll
            for (int ks = 0; ks < 4; ks++) {
                aR0 = __builtin_amdgcn_mfma_f32_16x16x32_bf16(ax[0][ks], biR[ks], aR0, 0, 0, 0);
                aR1 = __builtin_amdgcn_mfma_f32_16x16x32_bf16(ax[1][ks], biR[ks], aR1, 0, 0, 0);
                aR0 = __builtin_amdgcn_mfma_f32_16x16x32_bf16(ah[0][ks], bhR[ks], aR0, 0, 0, 0);
                aR1 = __builtin_amdgcn_mfma_f32_16x16x32_bf16(ah[1][ks], bhR[ks], aR1, 0, 0, 0);
            }
            if (t < 7) WLOAD(biR, bhR, 0, t + 1)   // prefetch R(t+1)
#pragma unroll
            for (int ks = 0; ks < 4; ks++) {
                aZ0 = __builtin_amdgcn_mfma_f32_16x16x32_bf16(ax[0][ks], biZ[ks], aZ0, 0, 0, 0);
                aZ1 = __builtin_amdgcn_mfma_f32_16x16x32_bf16(ax[1][ks], biZ[ks], aZ1, 0, 0, 0);
                aZ0 = __builtin_amdgcn_mfma_f32_16x16x32_bf16(ah[0][ks], bhZ[ks], aZ0, 0, 0, 0);
                aZ1 = __builtin_amdgcn_mfma_f32_16x16x32_bf16(ah[1][ks], bhZ[ks], aZ1, 0, 0, 0);
            }
            if (t < 7) WLOAD(biZ, bhZ, 1, t + 1)   // prefetch Z(t+1)
#pragma unroll
            for (int ks = 0; ks < 4; ks++) {
                aI0 = __builtin_amdgcn_mfma_f32_16x16x32_bf16(ax[0][ks], biN[ks], aI0, 0, 0, 0);
                aI1 = __builtin_amdgcn_mfma_f32_16x16x32_bf16(ax[1][ks], biN[ks], aI1, 0, 0, 0);
                aH0 = __builtin_amdgcn_mfma_f32_16x16x32_bf16(ah[0][ks], bhN[ks], aH0, 0, 0, 0);
                aH1 = __builtin_amdgcn_mfma_f32_16x16x32_bf16(ah[1][ks], bhN[ks], aH1, 0, 0, 0);
            }

            // epilogue for col-tile t
            int gcol = t * 16 + lr;
            float br = bih[gcol], bz = bih[DH + gcol], bn = bih[2 * DH + gcol];
            float cr = bhh[gcol], cz = bhh[DH + gcol], cn = bhh[2 * DH + gcol];
#pragma unroll
            for (int rt = 0; rt < 2; rt++) {
                f32x4 R = rt ? aR1 : aR0;
                f32x4 Z = rt ? aZ1 : aZ0;
                f32x4 I = rt ? aI1 : aI0;
                f32x4 Hn = rt ? aH1 : aH0;
#pragma unroll
                for (int j = 0; j < 4; j++) {
                    int grow = row0 + rt * 16 + kg * 4 + j;
                    if (grow < N) {
                        float hv = Hs[(size_t)grow * DH + gcol];
                        float r = 1.f / (1.f + __expf(-(R[j] + br + cr)));
                        float z = 1.f / (1.f + __expf(-(Z[j] + bz + cz)));
                        float n = tanhf(I[j] + bn + r * (Hn[j] + cn));
                        out[(size_t)grow * DH + gcol] = (1.f - z) * n + z * hv;
                    }
                }
            }
        }
#undef WLOAD
    }
}

extern "C" void kernel_launch(void* const* d_in, const int* in_sizes, int n_in,
                              void* d_out, int out_size, void* d_ws, size_t ws_size,
                              hipStream_t stream) {
    const float* x    = (const float*)d_in[0];
    const int*   ei   = (const int*)d_in[1];
    const float* h1   = (const float*)d_in[2];
    const float* h2   = (const float*)d_in[3];
    const float* h3   = (const float*)d_in[4];
    const float* g1w  = (const float*)d_in[5];
    const float* g1b  = (const float*)d_in[6];
    const float* g2w  = (const float*)d_in[7];
    const float* g2b  = (const float*)d_in[8];
    const float* wih1 = (const float*)d_in[9];
    const float* whh1 = (const float*)d_in[10];
    const float* bih1 = (const float*)d_in[11];
    const float* bhh1 = (const float*)d_in[12];
    const float* wih2 = (const float*)d_in[13];
    const float* whh2 = (const float*)d_in[14];
    const float* bih2 = (const float*)d_in[15];
    const float* bhh2 = (const float*)d_in[16];
    const float* wih3 = (const float*)d_in[17];
    const float* whh3 = (const float*)d_in[18];
    const float* bih3 = (const float*)d_in[19];
    const float* bhh3 = (const float*)d_in[20];

    int N = in_sizes[0] / DH;
    int E = in_sizes[1] / 2;
    int B = (N + SCB - 1) / SCB;
    int nstripes = (N + 127) / 128;

    char* wsp = (char*)d_ws;
    auto alloc = [&](size_t bytes) -> char* {
        char* p = wsp;
        wsp += (bytes + 63) & ~(size_t)63;
        return p;
    };
    int* qs       = (int*)alloc(8 * 4);                // work-queue counters
    unsigned* cnt = (unsigned*)alloc((size_t)N * 4);
    int* offs     = (int*)alloc(((size_t)N + 1) * 4);
    int* cur      = (int*)alloc((size_t)N * 4);
    float* dinv   = (float*)alloc((size_t)N * 4);
    unsigned* bsum= (unsigned*)alloc(((size_t)B + 1) * 4);
    int* csr_src  = (int*)alloc((size_t)E * 4);
    float* xw     = (float*)alloc((size_t)N * DH * 4);
    float* x2     = (float*)alloc((size_t)N * DH * 4);
    short* w1t    = (short*)alloc((size_t)DH * DH * 2);
    short* w2t    = (short*)alloc((size_t)DH * DH * 2);
    const int WN = 3 * DH * DH;      // 49152
    short* wbAll  = (short*)alloc((size_t)6 * WN * 2);
    short* wb[6];
    for (int i = 0; i < 6; i++) wb[i] = wbAll + (size_t)i * WN;

    float* out  = (float*)d_out;
    float* h1n  = out;
    float* h2n  = out + (size_t)N * DH;
    float* h3n  = out + 2 * (size_t)N * DH;

    // ---- reset queues ----
    hipMemsetAsync(qs, 0, 8 * 4, stream);

    // ---- weight prep (bf16) ----
    f2bf6_k<<<(6 * WN + 255) / 256, 256, 0, stream>>>(wih1, whh1, wih2, whh2, wih3, whh3, wbAll, WN);
    transpose_bf2_k<<<(2 * DH * DH + 255) / 256, 256, 0, stream>>>(g1w, g2w, w1t, w2t);

    // ---- CSR build (per call; deterministic) ----
    hipMemsetAsync(cnt, 0, (size_t)N * 4, stream);
    deg_count_k<<<(E + 255) / 256, 256, 0, stream>>>(ei, E, cnt);
    scan1_k<<<B, 256, 0, stream>>>(cnt, N, offs, bsum);
    scan2_k<<<1, 1024, 0, stream>>>(bsum, B);
    scan3_k<<<(N + 255) / 256, 256, 0, stream>>>(offs, cur, dinv, cnt, bsum, N, B);
    fill_k<<<(E + 255) / 256, 256, 0, stream>>>(ei, E, cur, csr_src);

    int gblocks = (N + 3) / 4;

    // ---- GCN layer 1 ----
    gemm_mfma_k<<<1024, 256, 0, stream>>>(x, w1t, xw, N, nstripes, qs + 0);
    gather_k<<<gblocks, 256, 0, stream>>>(csr_src, offs, dinv, xw, g1b, x2, N);

    // ---- GCN layer 2 ----
    gemm_mfma_k<<<1024, 256, 0, stream>>>(x2, w2t, xw, N, nstripes, qs + 1);
    gather_k<<<gblocks, 256, 0, stream>>>(csr_src, offs, dinv, xw, g2b, x2, N);

    // ---- GRU chain ----
    gru_mfma_k<<<512, 256, 0, stream>>>(x2,  h1, wb[0], wb[1], bih1, bhh1, h1n, N, nstripes, qs + 2);
    gru_mfma_k<<<512, 256, 0, stream>>>(h1n, h2, wb[2], wb[3], bih2, bhh2, h2n, N, nstripes, qs + 3);
    gru_mfma_k<<<512, 256, 0, stream>>>(h2n, h3, wb[4], wb[5], bih3, bhh3, h3n, N, nstripes, qs + 4);
}

// Round 8
// 876.795 us; speedup vs baseline: 1.2986x; 1.1830x over previous
//
#include <hip/hip_runtime.h>
#include <hip/hip_bf16.h>

#define DH 128          // feature dim (D_IN == H == 128)
#define SCB 1024        // scan elements per block

typedef __attribute__((ext_vector_type(8))) short short8_t;
typedef __attribute__((ext_vector_type(4))) float f32x4;

static __device__ __forceinline__ short f2bf(float f) {
    union { float f; unsigned u; } v; v.f = f;
    unsigned r = v.u + 0x7fffu + ((v.u >> 16) & 1u);   // RNE
    return (short)(r >> 16);
}

static __device__ __forceinline__ float bf2f(unsigned short b) {
    union { unsigned u; float f; } v; v.u = ((unsigned)b) << 16;
    return v.f;
}

static __device__ __forceinline__ short8_t cvt8(const float* p) {
    float4 a0 = *(const float4*)p;
    float4 a1 = *(const float4*)(p + 4);
    short8_t t;
    t[0] = f2bf(a0.x); t[1] = f2bf(a0.y); t[2] = f2bf(a0.z); t[3] = f2bf(a0.w);
    t[4] = f2bf(a1.x); t[5] = f2bf(a1.y); t[6] = f2bf(a1.z); t[7] = f2bf(a1.w);
    return t;
}

// ---------------- degree histogram ----------------
__global__ void deg_count_k(const int* __restrict__ ei, int E, unsigned* __restrict__ cnt) {
    int e = blockIdx.x * 256 + threadIdx.x;
    if (e < E) atomicAdd(&cnt[ei[E + e]], 1u);
}

// ---------------- 3-phase grid-parallel exclusive scan ----------------
__global__ __launch_bounds__(256) void scan1_k(const unsigned* __restrict__ cnt, int N,
                                               int* __restrict__ offs, unsigned* __restrict__ bsum) {
    __shared__ unsigned s[256];
    int t = threadIdx.x;
    int i0 = blockIdx.x * SCB + t * 4;
    unsigned v0 = (i0 + 0 < N) ? cnt[i0 + 0] : 0u;
    unsigned v1 = (i0 + 1 < N) ? cnt[i0 + 1] : 0u;
    unsigned v2 = (i0 + 2 < N) ? cnt[i0 + 2] : 0u;
    unsigned v3 = (i0 + 3 < N) ? cnt[i0 + 3] : 0u;
    unsigned ts = v0 + v1 + v2 + v3;
    s[t] = ts;
    __syncthreads();
    for (int off = 1; off < 256; off <<= 1) {
        unsigned u = (t >= off) ? s[t - off] : 0u;
        __syncthreads();
        s[t] += u;
        __syncthreads();
    }
    unsigned ex = s[t] - ts;
    if (i0 + 0 < N) offs[i0 + 0] = (int)ex;
    if (i0 + 1 < N) offs[i0 + 1] = (int)(ex + v0);
    if (i0 + 2 < N) offs[i0 + 2] = (int)(ex + v0 + v1);
    if (i0 + 3 < N) offs[i0 + 3] = (int)(ex + v0 + v1 + v2);
    if (t == 255) bsum[blockIdx.x] = s[255];
}

__global__ __launch_bounds__(1024) void scan2_k(unsigned* __restrict__ bsum, int B) {
    __shared__ unsigned s[1024];
    int t = threadIdx.x;
    unsigned v = (t < B) ? bsum[t] : 0u;
    s[t] = v;
    __syncthreads();
    for (int off = 1; off < 1024; off <<= 1) {
        unsigned u = (t >= off) ? s[t - off] : 0u;
        __syncthreads();
        s[t] += u;
        __syncthreads();
    }
    if (t < B) bsum[t] = s[t] - v;
    if (t == 0) bsum[B] = s[1023];
}

__global__ void scan3_k(int* __restrict__ offs, int* __restrict__ cur,
                        float* __restrict__ dinv, const unsigned* __restrict__ cnt,
                        const unsigned* __restrict__ bsum, int N, int B) {
    int i = blockIdx.x * 256 + threadIdx.x;
    if (i < N) {
        int v = offs[i] + (int)bsum[i >> 10];
        offs[i] = v;
        cur[i] = v;
        dinv[i] = rsqrtf((float)cnt[i] + 1.0f);
    }
    if (i == 0) offs[N] = (int)bsum[B];
}

// ---------------- CSR fill: edges bucketed by dst ----------------
__global__ void fill_k(const int* __restrict__ ei, int E,
                       int* __restrict__ cur, int* __restrict__ csr_src) {
    int e = blockIdx.x * 256 + threadIdx.x;
    if (e < E) {
        int d = ei[E + e];
        int pos = atomicAdd(&cur[d], 1);
        csr_src[pos] = ei[e];
    }
}

// ---------------- weight prep ----------------
__global__ void f2bf6_k(const float* __restrict__ s0, const float* __restrict__ s1,
                        const float* __restrict__ s2, const float* __restrict__ s3,
                        const float* __restrict__ s4, const float* __restrict__ s5,
                        short* __restrict__ dst, int WN) {
    int i = blockIdx.x * 256 + threadIdx.x;
    if (i >= 6 * WN) return;
    int b = i / WN, r = i - b * WN;
    const float* srcs[6] = {s0, s1, s2, s3, s4, s5};
    dst[i] = f2bf(srcs[b][r]);
}

__global__ void transpose_bf2_k(const float* __restrict__ sa, const float* __restrict__ sb,
                                short* __restrict__ da, short* __restrict__ db) {
    int i = blockIdx.x * 256 + threadIdx.x;   // 2*16384
    int m = i >> 14;
    int j = i & 16383;
    int c = j >> 7, k = j & 127;
    const float* s = m ? sb : sa;
    short* d = m ? db : da;
    d[j] = f2bf(s[k * DH + c]);
}

// ================= MFMA GEMM, register-streamed weights, depth-2 prefetch ===========
// C[N,128](bf16) = A[N,128](fp32) @ Wt^T, Wt bf16 [c][k]. 256 thr / 4 waves,
// one 128-row stripe per block (blockIdx). Weight tile t prefetched 2 ahead (slot t%3).
__global__ __launch_bounds__(256, 4) void gemm_mfma_k(const float* __restrict__ A,
                                                      const short* __restrict__ Wt,
                                                      short* __restrict__ C, int N) {
    int tid = threadIdx.x;
    int wave = tid >> 6, lane = tid & 63;
    int lr = lane & 15, kg = lane >> 4;

    int row0 = blockIdx.x * 128 + wave * 32;
    int ar0 = min(row0 + lr, N - 1);
    int ar1 = min(row0 + 16 + lr, N - 1);
    const float* a0p = A + (size_t)ar0 * DH;
    const float* a1p = A + (size_t)ar1 * DH;
    short8_t af[2][4];
#pragma unroll
    for (int ks = 0; ks < 4; ks++) {
        af[0][ks] = cvt8(a0p + ks * 32 + kg * 8);
        af[1][ks] = cvt8(a1p + ks * 32 + kg * 8);
    }

    short8_t bt[3][4];
#define GLOADW(slot, t) { \
    const short* wp = Wt + (size_t)((t) * 16 + lr) * DH + kg * 8; \
    bt[slot][0] = *(const short8_t*)(wp); \
    bt[slot][1] = *(const short8_t*)(wp + 32); \
    bt[slot][2] = *(const short8_t*)(wp + 64); \
    bt[slot][3] = *(const short8_t*)(wp + 96); }

    GLOADW(0, 0)
    GLOADW(1, 1)
#pragma unroll
    for (int t = 0; t < 8; t++) {
        if (t < 6) GLOADW((t + 2) % 3, t + 2)
        f32x4 acc0 = {0.f, 0.f, 0.f, 0.f};
        f32x4 acc1 = {0.f, 0.f, 0.f, 0.f};
#pragma unroll
        for (int ks = 0; ks < 4; ks++) {
            acc0 = __builtin_amdgcn_mfma_f32_16x16x32_bf16(af[0][ks], bt[t % 3][ks], acc0, 0, 0, 0);
            acc1 = __builtin_amdgcn_mfma_f32_16x16x32_bf16(af[1][ks], bt[t % 3][ks], acc1, 0, 0, 0);
        }
        int col = t * 16 + lr;
#pragma unroll
        for (int j = 0; j < 4; j++) {
            int g0 = row0 + kg * 4 + j;
            int g1 = row0 + 16 + kg * 4 + j;
            if (g0 < N) C[(size_t)g0 * DH + col] = f2bf(acc0[j]);
            if (g1 < N) C[(size_t)g1 * DH + col] = f2bf(acc1[j]);
        }
    }
#undef GLOADW
}

// ---------------- gather: bf16 xw table, fp32 output ----------------
// dest[d] = relu( sum_e xw[src_e]*dinv[src_e]*dinv[d] + xw[d]*dinv[d]^2 + b )
__global__ __launch_bounds__(256) void gather_k(const int* __restrict__ csr_src,
                                                const int* __restrict__ offs,
                                                const float* __restrict__ dinv,
                                                const unsigned* __restrict__ xwb,  // bf16x2 per uint
                                                const float* __restrict__ bias,
                                                float* __restrict__ dest, int N) {
    int wid = blockIdx.x * 4 + (threadIdx.x >> 6);
    if (wid >= N) return;
    int lane = threadIdx.x & 63;
    int j = offs[wid];
    int end = offs[wid + 1];
    float dd = dinv[wid];
    float ax = 0.f, ay = 0.f;

    if (j < end) {
        int s = csr_src[j];
        float dv = dinv[s];
        for (; j + 1 < end; ++j) {
            int sn = csr_src[j + 1];
            float dvn = dinv[sn];
            unsigned v = xwb[(size_t)s * 64 + lane];
            float nrm = dd * dv;
            ax = fmaf(bf2f((unsigned short)(v & 0xffffu)), nrm, ax);
            ay = fmaf(bf2f((unsigned short)(v >> 16)), nrm, ay);
            s = sn; dv = dvn;
        }
        unsigned v = xwb[(size_t)s * 64 + lane];
        float nrm = dd * dv;
        ax = fmaf(bf2f((unsigned short)(v & 0xffffu)), nrm, ax);
        ay = fmaf(bf2f((unsigned short)(v >> 16)), nrm, ay);
    }

    unsigned xv = xwb[(size_t)wid * 64 + lane];
    float2 b2 = ((const float2*)bias)[lane];
    float sl = dd * dd;
    float ox = fmaxf(fmaf(bf2f((unsigned short)(xv & 0xffffu)), sl, ax) + b2.x, 0.f);
    float oy = fmaxf(fmaf(bf2f((unsigned short)(xv >> 16)), sl, ay) + b2.y, 0.f);
    float2 o; o.x = ox; o.y = oy;
    ((float2*)dest)[(size_t)wid * 64 + lane] = o;
}

// ================= fused MFMA GRU cell, depth-2 weight prefetch ====================
// wih/whh bf16 [384][128]. 256 thr / 4 waves, one 128-row stripe per block.
__global__ __launch_bounds__(256, 2) void gru_mfma_k(const float* __restrict__ X,
                                                     const float* __restrict__ Hs,
                                                     const short* __restrict__ wih,
                                                     const short* __restrict__ whh,
                                                     const float* __restrict__ bih,
                                                     const float* __restrict__ bhh,
                                                     float* __restrict__ out, int N) {
    int tid = threadIdx.x;
    int wave = tid >> 6, lane = tid & 63;
    int lr = lane & 15, kg = lane >> 4;

    int row0 = blockIdx.x * 128 + wave * 32;
    int ar0 = min(row0 + lr, N - 1);
    int ar1 = min(row0 + 16 + lr, N - 1);
    const float* x0 = X + (size_t)ar0 * DH;
    const float* x1 = X + (size_t)ar1 * DH;
    const float* h0 = Hs + (size_t)ar0 * DH;
    const float* h1p = Hs + (size_t)ar1 * DH;

    short8_t ax[2][4], ah[2][4];
#pragma unroll
    for (int ks = 0; ks < 4; ks++) {
        int ko = ks * 32 + kg * 8;
        ax[0][ks] = cvt8(x0 + ko);
        ax[1][ks] = cvt8(x1 + ko);
        ah[0][ks] = cvt8(h0 + ko);
        ah[1][ks] = cvt8(h1p + ko);
    }

    short8_t biR[4], bhR[4], biZ[4], bhZ[4], biN[4], bhN[4];
#define WLOAD(bi_, bh_, g, t) { \
    const short* wi_ = wih + (size_t)((g) * DH + (t) * 16 + lr) * DH + kg * 8; \
    const short* wh_ = whh + (size_t)((g) * DH + (t) * 16 + lr) * DH + kg * 8; \
    bi_[0] = *(const short8_t*)(wi_);      bh_[0] = *(const short8_t*)(wh_); \
    bi_[1] = *(const short8_t*)(wi_ + 32); bh_[1] = *(const short8_t*)(wh_ + 32); \
    bi_[2] = *(const short8_t*)(wi_ + 64); bh_[2] = *(const short8_t*)(wh_ + 64); \
    bi_[3] = *(const short8_t*)(wi_ + 96); bh_[3] = *(const short8_t*)(wh_ + 96); }

    WLOAD(biR, bhR, 0, 0)           // R(0)
    WLOAD(biZ, bhZ, 1, 0)           // Z(0)
#pragma unroll
    for (int t = 0; t < 8; t++) {
        f32x4 aR0 = {0,0,0,0}, aR1 = {0,0,0,0};
        f32x4 aZ0 = {0,0,0,0}, aZ1 = {0,0,0,0};
        f32x4 aI0 = {0,0,0,0}, aI1 = {0,0,0,0};
        f32x4 aH0 = {0,0,0,0}, aH1 = {0,0,0,0};

        WLOAD(biN, bhN, 2, t)       // prefetch N(t)
#pragma unroll
        for (int ks = 0; ks < 4; ks++) {
            aR0 = __builtin_amdgcn_mfma_f32_16x16x32_bf16(ax[0][ks], biR[ks], aR0, 0, 0, 0);
            aR1 = __builtin_amdgcn_mfma_f32_16x16x32_bf16(ax[1][ks], biR[ks], aR1, 0, 0, 0);
            aR0 = __builtin_amdgcn_mfma_f32_16x16x32_bf16(ah[0][ks], bhR[ks], aR0, 0, 0, 0);
            aR1 = __builtin_amdgcn_mfma_f32_16x16x32_bf16(ah[1][ks], bhR[ks], aR1, 0, 0, 0);
        }
        if (t < 7) WLOAD(biR, bhR, 0, t + 1)   // prefetch R(t+1)
#pragma unroll
        for (int ks = 0; ks < 4; ks++) {
            aZ0 = __builtin_amdgcn_mfma_f32_16x16x32_bf16(ax[0][ks], biZ[ks], aZ0, 0, 0, 0);
            aZ1 = __builtin_amdgcn_mfma_f32_16x16x32_bf16(ax[1][ks], biZ[ks], aZ1, 0, 0, 0);
            aZ0 = __builtin_amdgcn_mfma_f32_16x16x32_bf16(ah[0][ks], bhZ[ks], aZ0, 0, 0, 0);
            aZ1 = __builtin_amdgcn_mfma_f32_16x16x32_bf16(ah[1][ks], bhZ[ks], aZ1, 0, 0, 0);
        }
        if (t < 7) WLOAD(biZ, bhZ, 1, t + 1)   // prefetch Z(t+1)
#pragma unroll
        for (int ks = 0; ks < 4; ks++) {
            aI0 = __builtin_amdgcn_mfma_f32_16x16x32_bf16(ax[0][ks], biN[ks], aI0, 0, 0, 0);
            aI1 = __builtin_amdgcn_mfma_f32_16x16x32_bf16(ax[1][ks], biN[ks], aI1, 0, 0, 0);
            aH0 = __builtin_amdgcn_mfma_f32_16x16x32_bf16(ah[0][ks], bhN[ks], aH0, 0, 0, 0);
            aH1 = __builtin_amdgcn_mfma_f32_16x16x32_bf16(ah[1][ks], bhN[ks], aH1, 0, 0, 0);
        }

        // epilogue for col-tile t
        int gcol = t * 16 + lr;
        float br = bih[gcol], bz = bih[DH + gcol], bn = bih[2 * DH + gcol];
        float cr = bhh[gcol], cz = bhh[DH + gcol], cn = bhh[2 * DH + gcol];
#pragma unroll
        for (int rt = 0; rt < 2; rt++) {
            f32x4 R = rt ? aR1 : aR0;
            f32x4 Z = rt ? aZ1 : aZ0;
            f32x4 I = rt ? aI1 : aI0;
            f32x4 Hn = rt ? aH1 : aH0;
#pragma unroll
            for (int j = 0; j < 4; j++) {
                int grow = row0 + rt * 16 + kg * 4 + j;
                if (grow < N) {
                    float hv = Hs[(size_t)grow * DH + gcol];
                    float r = 1.f / (1.f + __expf(-(R[j] + br + cr)));
                    float z = 1.f / (1.f + __expf(-(Z[j] + bz + cz)));
                    float n = tanhf(I[j] + bn + r * (Hn[j] + cn));
                    out[(size_t)grow * DH + gcol] = (1.f - z) * n + z * hv;
                }
            }
        }
    }
#undef WLOAD
}

extern "C" void kernel_launch(void* const* d_in, const int* in_sizes, int n_in,
                              void* d_out, int out_size, void* d_ws, size_t ws_size,
                              hipStream_t stream) {
    const float* x    = (const float*)d_in[0];
    const int*   ei   = (const int*)d_in[1];
    const float* h1   = (const float*)d_in[2];
    const float* h2   = (const float*)d_in[3];
    const float* h3   = (const float*)d_in[4];
    const float* g1w  = (const float*)d_in[5];
    const float* g1b  = (const float*)d_in[6];
    const float* g2w  = (const float*)d_in[7];
    const float* g2b  = (const float*)d_in[8];
    const float* wih1 = (const float*)d_in[9];
    const float* whh1 = (const float*)d_in[10];
    const float* bih1 = (const float*)d_in[11];
    const float* bhh1 = (const float*)d_in[12];
    const float* wih2 = (const float*)d_in[13];
    const float* whh2 = (const float*)d_in[14];
    const float* bih2 = (const float*)d_in[15];
    const float* bhh2 = (const float*)d_in[16];
    const float* wih3 = (const float*)d_in[17];
    const float* whh3 = (const float*)d_in[18];
    const float* bih3 = (const float*)d_in[19];
    const float* bhh3 = (const float*)d_in[20];

    int N = in_sizes[0] / DH;
    int E = in_sizes[1] / 2;
    int B = (N + SCB - 1) / SCB;
    int nstripes = (N + 127) / 128;

    char* wsp = (char*)d_ws;
    auto alloc = [&](size_t bytes) -> char* {
        char* p = wsp;
        wsp += (bytes + 63) & ~(size_t)63;
        return p;
    };
    unsigned* cnt = (unsigned*)alloc((size_t)N * 4);
    int* offs     = (int*)alloc(((size_t)N + 1) * 4);
    int* cur      = (int*)alloc((size_t)N * 4);
    float* dinv   = (float*)alloc((size_t)N * 4);
    unsigned* bsum= (unsigned*)alloc(((size_t)B + 1) * 4);
    int* csr_src  = (int*)alloc((size_t)E * 4);
    short* xwb    = (short*)alloc((size_t)N * DH * 2);   // bf16 xw table
    float* x2     = (float*)alloc((size_t)N * DH * 4);
    short* w1t    = (short*)alloc((size_t)DH * DH * 2);
    short* w2t    = (short*)alloc((size_t)DH * DH * 2);
    const int WN = 3 * DH * DH;      // 49152
    short* wbAll  = (short*)alloc((size_t)6 * WN * 2);
    short* wb[6];
    for (int i = 0; i < 6; i++) wb[i] = wbAll + (size_t)i * WN;

    float* out  = (float*)d_out;
    float* h1n  = out;
    float* h2n  = out + (size_t)N * DH;
    float* h3n  = out + 2 * (size_t)N * DH;

    // ---- weight prep (bf16) ----
    f2bf6_k<<<(6 * WN + 255) / 256, 256, 0, stream>>>(wih1, whh1, wih2, whh2, wih3, whh3, wbAll, WN);
    transpose_bf2_k<<<(2 * DH * DH + 255) / 256, 256, 0, stream>>>(g1w, g2w, w1t, w2t);

    // ---- CSR build (per call; deterministic) ----
    hipMemsetAsync(cnt, 0, (size_t)N * 4, stream);
    deg_count_k<<<(E + 255) / 256, 256, 0, stream>>>(ei, E, cnt);
    scan1_k<<<B, 256, 0, stream>>>(cnt, N, offs, bsum);
    scan2_k<<<1, 1024, 0, stream>>>(bsum, B);
    scan3_k<<<(N + 255) / 256, 256, 0, stream>>>(offs, cur, dinv, cnt, bsum, N, B);
    fill_k<<<(E + 255) / 256, 256, 0, stream>>>(ei, E, cur, csr_src);

    int gblocks = (N + 3) / 4;

    // ---- GCN layer 1 ----
    gemm_mfma_k<<<nstripes, 256, 0, stream>>>(x, w1t, xwb, N);
    gather_k<<<gblocks, 256, 0, stream>>>(csr_src, offs, dinv, (const unsigned*)xwb, g1b, x2, N);

    // ---- GCN layer 2 ----
    gemm_mfma_k<<<nstripes, 256, 0, stream>>>(x2, w2t, xwb, N);
    gather_k<<<gblocks, 256, 0, stream>>>(csr_src, offs, dinv, (const unsigned*)xwb, g2b, x2, N);

    // ---- GRU chain ----
    gru_mfma_k<<<nstripes, 256, 0, stream>>>(x2,  h1, wb[0], wb[1], bih1, bhh1, h1n, N);
    gru_mfma_k<<<nstripes, 256, 0, stream>>>(h1n, h2, wb[2], wb[3], bih2, bhh2, h2n, N);
    gru_mfma_k<<<nstripes, 256, 0, stream>>>(h2n, h3, wb[4], wb[5], bih3, bhh3, h3n, N);
}

// Round 9
// 827.280 us; speedup vs baseline: 1.3763x; 1.0599x over previous
//
#include <hip/hip_runtime.h>
#include <hip/hip_bf16.h>

#define DH 128          // feature dim (D_IN == H == 128)
#define SCB 1024        // scan elements per block
#define NCHUNK 256      // edge chunks for XCD-partitioned CSR build

typedef __attribute__((ext_vector_type(8))) short short8_t;
typedef __attribute__((ext_vector_type(4))) float f32x4;

static __device__ __forceinline__ short f2bf(float f) {
    union { float f; unsigned u; } v; v.f = f;
    unsigned r = v.u + 0x7fffu + ((v.u >> 16) & 1u);   // RNE
    return (short)(r >> 16);
}

static __device__ __forceinline__ float bf2f(unsigned short b) {
    union { unsigned u; float f; } v; v.u = ((unsigned)b) << 16;
    return v.f;
}

static __device__ __forceinline__ short8_t cvt8(const float* p) {
    float4 a0 = *(const float4*)p;
    float4 a1 = *(const float4*)(p + 4);
    short8_t t;
    t[0] = f2bf(a0.x); t[1] = f2bf(a0.y); t[2] = f2bf(a0.z); t[3] = f2bf(a0.w);
    t[4] = f2bf(a1.x); t[5] = f2bf(a1.y); t[6] = f2bf(a1.z); t[7] = f2bf(a1.w);
    return t;
}

// ---------------- degree histogram, XCD-partitioned ----------------
// block (c, r): scans edge chunk c, counts only dst in range r.
// r == blockIdx&7 == XCD (round-robin dispatch heuristic) -> cnt lines stay in one L2.
__global__ __launch_bounds__(256) void deg2_k(const int* __restrict__ ei, int E,
                                              unsigned* __restrict__ cnt, int span, int chunkE) {
    int r = blockIdx.x & 7;
    int c = blockIdx.x >> 3;
    int lo = r * span, hi = lo + span;
    long long e0 = (long long)c * chunkE;
    long long e1 = e0 + chunkE; if (e1 > E) e1 = E;
    for (long long e = e0 + threadIdx.x; e < e1; e += 256) {
        int d = ei[E + e];
        if (d >= lo && d < hi) atomicAdd(&cnt[d], 1u);
    }
}

// ---------------- 3-phase grid-parallel exclusive scan ----------------
__global__ __launch_bounds__(256) void scan1_k(const unsigned* __restrict__ cnt, int N,
                                               int* __restrict__ offs, unsigned* __restrict__ bsum) {
    __shared__ unsigned s[256];
    int t = threadIdx.x;
    int i0 = blockIdx.x * SCB + t * 4;
    unsigned v0 = (i0 + 0 < N) ? cnt[i0 + 0] : 0u;
    unsigned v1 = (i0 + 1 < N) ? cnt[i0 + 1] : 0u;
    unsigned v2 = (i0 + 2 < N) ? cnt[i0 + 2] : 0u;
    unsigned v3 = (i0 + 3 < N) ? cnt[i0 + 3] : 0u;
    unsigned ts = v0 + v1 + v2 + v3;
    s[t] = ts;
    __syncthreads();
    for (int off = 1; off < 256; off <<= 1) {
        unsigned u = (t >= off) ? s[t - off] : 0u;
        __syncthreads();
        s[t] += u;
        __syncthreads();
    }
    unsigned ex = s[t] - ts;
    if (i0 + 0 < N) offs[i0 + 0] = (int)ex;
    if (i0 + 1 < N) offs[i0 + 1] = (int)(ex + v0);
    if (i0 + 2 < N) offs[i0 + 2] = (int)(ex + v0 + v1);
    if (i0 + 3 < N) offs[i0 + 3] = (int)(ex + v0 + v1 + v2);
    if (t == 255) bsum[blockIdx.x] = s[255];
}

__global__ __launch_bounds__(1024) void scan2_k(unsigned* __restrict__ bsum, int B) {
    __shared__ unsigned s[1024];
    int t = threadIdx.x;
    unsigned v = (t < B) ? bsum[t] : 0u;
    s[t] = v;
    __syncthreads();
    for (int off = 1; off < 1024; off <<= 1) {
        unsigned u = (t >= off) ? s[t - off] : 0u;
        __syncthreads();
        s[t] += u;
        __syncthreads();
    }
    if (t < B) bsum[t] = s[t] - v;
    if (t == 0) bsum[B] = s[1023];
}

__global__ void scan3_k(int* __restrict__ offs, int* __restrict__ cur,
                        float* __restrict__ dinv, const unsigned* __restrict__ cnt,
                        const unsigned* __restrict__ bsum, int N, int B) {
    int i = blockIdx.x * 256 + threadIdx.x;
    if (i < N) {
        int v = offs[i] + (int)bsum[i >> 10];
        offs[i] = v;
        cur[i] = v;
        dinv[i] = rsqrtf((float)cnt[i] + 1.0f);
    }
    if (i == 0) offs[N] = (int)bsum[B];
}

// ---------------- CSR fill, XCD-partitioned ----------------
// block (c, r): scans edge chunk c, inserts only edges with dst in range r.
// csr_src/cur lines for range r are written only from XCD r -> no line ping-pong.
__global__ __launch_bounds__(256) void fill2_k(const int* __restrict__ ei, int E,
                                               int* __restrict__ cur, int* __restrict__ csr_src,
                                               int span, int chunkE) {
    int r = blockIdx.x & 7;
    int c = blockIdx.x >> 3;
    int lo = r * span, hi = lo + span;
    long long e0 = (long long)c * chunkE;
    long long e1 = e0 + chunkE; if (e1 > E) e1 = E;
    for (long long e = e0 + threadIdx.x; e < e1; e += 256) {
        int d = ei[E + e];
        if (d >= lo && d < hi) {
            int pos = atomicAdd(&cur[d], 1);
            csr_src[pos] = ei[e];
        }
    }
}

// ---------------- weight prep ----------------
__global__ void f2bf6_k(const float* __restrict__ s0, const float* __restrict__ s1,
                        const float* __restrict__ s2, const float* __restrict__ s3,
                        const float* __restrict__ s4, const float* __restrict__ s5,
                        short* __restrict__ dst, int WN) {
    int i = blockIdx.x * 256 + threadIdx.x;
    if (i >= 6 * WN) return;
    int b = i / WN, r = i - b * WN;
    const float* srcs[6] = {s0, s1, s2, s3, s4, s5};
    dst[i] = f2bf(srcs[b][r]);
}

__global__ void transpose_bf2_k(const float* __restrict__ sa, const float* __restrict__ sb,
                                short* __restrict__ da, short* __restrict__ db) {
    int i = blockIdx.x * 256 + threadIdx.x;   // 2*16384
    int m = i >> 14;
    int j = i & 16383;
    int c = j >> 7, k = j & 127;
    const float* s = m ? sb : sa;
    short* d = m ? db : da;
    d[j] = f2bf(s[k * DH + c]);
}

// ================= MFMA GEMM, register-streamed weights, depth-2 prefetch ===========
__global__ __launch_bounds__(256, 4) void gemm_mfma_k(const float* __restrict__ A,
                                                      const short* __restrict__ Wt,
                                                      short* __restrict__ C, int N) {
    int tid = threadIdx.x;
    int wave = tid >> 6, lane = tid & 63;
    int lr = lane & 15, kg = lane >> 4;

    int row0 = blockIdx.x * 128 + wave * 32;
    int ar0 = min(row0 + lr, N - 1);
    int ar1 = min(row0 + 16 + lr, N - 1);
    const float* a0p = A + (size_t)ar0 * DH;
    const float* a1p = A + (size_t)ar1 * DH;
    short8_t af[2][4];
#pragma unroll
    for (int ks = 0; ks < 4; ks++) {
        af[0][ks] = cvt8(a0p + ks * 32 + kg * 8);
        af[1][ks] = cvt8(a1p + ks * 32 + kg * 8);
    }

    short8_t bt[3][4];
#define GLOADW(slot, t) { \
    const short* wp = Wt + (size_t)((t) * 16 + lr) * DH + kg * 8; \
    bt[slot][0] = *(const short8_t*)(wp); \
    bt[slot][1] = *(const short8_t*)(wp + 32); \
    bt[slot][2] = *(const short8_t*)(wp + 64); \
    bt[slot][3] = *(const short8_t*)(wp + 96); }

    GLOADW(0, 0)
    GLOADW(1, 1)
#pragma unroll
    for (int t = 0; t < 8; t++) {
        if (t < 6) GLOADW((t + 2) % 3, t + 2)
        f32x4 acc0 = {0.f, 0.f, 0.f, 0.f};
        f32x4 acc1 = {0.f, 0.f, 0.f, 0.f};
#pragma unroll
        for (int ks = 0; ks < 4; ks++) {
            acc0 = __builtin_amdgcn_mfma_f32_16x16x32_bf16(af[0][ks], bt[t % 3][ks], acc0, 0, 0, 0);
            acc1 = __builtin_amdgcn_mfma_f32_16x16x32_bf16(af[1][ks], bt[t % 3][ks], acc1, 0, 0, 0);
        }
        int col = t * 16 + lr;
#pragma unroll
        for (int j = 0; j < 4; j++) {
            int g0 = row0 + kg * 4 + j;
            int g1 = row0 + 16 + kg * 4 + j;
            if (g0 < N) C[(size_t)g0 * DH + col] = f2bf(acc0[j]);
            if (g1 < N) C[(size_t)g1 * DH + col] = f2bf(acc1[j]);
        }
    }
#undef GLOADW
}

// ---------------- gather: bf16 xw table, fp32 output ----------------
__global__ __launch_bounds__(256) void gather_k(const int* __restrict__ csr_src,
                                                const int* __restrict__ offs,
                                                const float* __restrict__ dinv,
                                                const unsigned* __restrict__ xwb,  // bf16x2 per uint
                                                const float* __restrict__ bias,
                                                float* __restrict__ dest, int N) {
    int wid = blockIdx.x * 4 + (threadIdx.x >> 6);
    if (wid >= N) return;
    int lane = threadIdx.x & 63;
    int j = offs[wid];
    int end = offs[wid + 1];
    float dd = dinv[wid];
    float ax = 0.f, ay = 0.f;

    if (j < end) {
        int s = csr_src[j];
        float dv = dinv[s];
        for (; j + 1 < end; ++j) {
            int sn = csr_src[j + 1];
            float dvn = dinv[sn];
            unsigned v = xwb[(size_t)s * 64 + lane];
            float nrm = dd * dv;
            ax = fmaf(bf2f((unsigned short)(v & 0xffffu)), nrm, ax);
            ay = fmaf(bf2f((unsigned short)(v >> 16)), nrm, ay);
            s = sn; dv = dvn;
        }
        unsigned v = xwb[(size_t)s * 64 + lane];
        float nrm = dd * dv;
        ax = fmaf(bf2f((unsigned short)(v & 0xffffu)), nrm, ax);
        ay = fmaf(bf2f((unsigned short)(v >> 16)), nrm, ay);
    }

    unsigned xv = xwb[(size_t)wid * 64 + lane];
    float2 b2 = ((const float2*)bias)[lane];
    float sl = dd * dd;
    float ox = fmaxf(fmaf(bf2f((unsigned short)(xv & 0xffffu)), sl, ax) + b2.x, 0.f);
    float oy = fmaxf(fmaf(bf2f((unsigned short)(xv >> 16)), sl, ay) + b2.y, 0.f);
    float2 o; o.x = ox; o.y = oy;
    ((float2*)dest)[(size_t)wid * 64 + lane] = o;
}

// ================= fused MFMA GRU cell, depth-2 weight prefetch ====================
__global__ __launch_bounds__(256, 2) void gru_mfma_k(const float* __restrict__ X,
                                                     const float* __restrict__ Hs,
                                                     const short* __restrict__ wih,
                                                     const short* __restrict__ whh,
                                                     const float* __restrict__ bih,
                                                     const float* __restrict__ bhh,
                                                     float* __restrict__ out, int N) {
    int tid = threadIdx.x;
    int wave = tid >> 6, lane = tid & 63;
    int lr = lane & 15, kg = lane >> 4;

    int row0 = blockIdx.x * 128 + wave * 32;
    int ar0 = min(row0 + lr, N - 1);
    int ar1 = min(row0 + 16 + lr, N - 1);
    const float* x0 = X + (size_t)ar0 * DH;
    const float* x1 = X + (size_t)ar1 * DH;
    const float* h0 = Hs + (size_t)ar0 * DH;
    const float* h1p = Hs + (size_t)ar1 * DH;

    short8_t ax[2][4], ah[2][4];
#pragma unroll
    for (int ks = 0; ks < 4; ks++) {
        int ko = ks * 32 + kg * 8;
        ax[0][ks] = cvt8(x0 + ko);
        ax[1][ks] = cvt8(x1 + ko);
        ah[0][ks] = cvt8(h0 + ko);
        ah[1][ks] = cvt8(h1p + ko);
    }

    short8_t biR[4], bhR[4], biZ[4], bhZ[4], biN[4], bhN[4];
#define WLOAD(bi_, bh_, g, t) { \
    const short* wi_ = wih + (size_t)((g) * DH + (t) * 16 + lr) * DH + kg * 8; \
    const short* wh_ = whh + (size_t)((g) * DH + (t) * 16 + lr) * DH + kg * 8; \
    bi_[0] = *(const short8_t*)(wi_);      bh_[0] = *(const short8_t*)(wh_); \
    bi_[1] = *(const short8_t*)(wi_ + 32); bh_[1] = *(const short8_t*)(wh_ + 32); \
    bi_[2] = *(const short8_t*)(wi_ + 64); bh_[2] = *(const short8_t*)(wh_ + 64); \
    bi_[3] = *(const short8_t*)(wi_ + 96); bh_[3] = *(const short8_t*)(wh_ + 96); }

    WLOAD(biR, bhR, 0, 0)           // R(0)
    WLOAD(biZ, bhZ, 1, 0)           // Z(0)
#pragma unroll
    for (int t = 0; t < 8; t++) {
        f32x4 aR0 = {0,0,0,0}, aR1 = {0,0,0,0};
        f32x4 aZ0 = {0,0,0,0}, aZ1 = {0,0,0,0};
        f32x4 aI0 = {0,0,0,0}, aI1 = {0,0,0,0};
        f32x4 aH0 = {0,0,0,0}, aH1 = {0,0,0,0};

        WLOAD(biN, bhN, 2, t)       // prefetch N(t)
#pragma unroll
        for (int ks = 0; ks < 4; ks++) {
            aR0 = __builtin_amdgcn_mfma_f32_16x16x32_bf16(ax[0][ks], biR[ks], aR0, 0, 0, 0);
            aR1 = __builtin_amdgcn_mfma_f32_16x16x32_bf16(ax[1][ks], biR[ks], aR1, 0, 0, 0);
            aR0 = __builtin_amdgcn_mfma_f32_16x16x32_bf16(ah[0][ks], bhR[ks], aR0, 0, 0, 0);
            aR1 = __builtin_amdgcn_mfma_f32_16x16x32_bf16(ah[1][ks], bhR[ks], aR1, 0, 0, 0);
        }
        if (t < 7) WLOAD(biR, bhR, 0, t + 1)   // prefetch R(t+1)
#pragma unroll
        for (int ks = 0; ks < 4; ks++) {
            aZ0 = __builtin_amdgcn_mfma_f32_16x16x32_bf16(ax[0][ks], biZ[ks], aZ0, 0, 0, 0);
            aZ1 = __builtin_amdgcn_mfma_f32_16x16x32_bf16(ax[1][ks], biZ[ks], aZ1, 0, 0, 0);
            aZ0 = __builtin_amdgcn_mfma_f32_16x16x32_bf16(ah[0][ks], bhZ[ks], aZ0, 0, 0, 0);
            aZ1 = __builtin_amdgcn_mfma_f32_16x16x32_bf16(ah[1][ks], bhZ[ks], aZ1, 0, 0, 0);
        }
        if (t < 7) WLOAD(biZ, bhZ, 1, t + 1)   // prefetch Z(t+1)
#pragma unroll
        for (int ks = 0; ks < 4; ks++) {
            aI0 = __builtin_amdgcn_mfma_f32_16x16x32_bf16(ax[0][ks], biN[ks], aI0, 0, 0, 0);
            aI1 = __builtin_amdgcn_mfma_f32_16x16x32_bf16(ax[1][ks], biN[ks], aI1, 0, 0, 0);
            aH0 = __builtin_amdgcn_mfma_f32_16x16x32_bf16(ah[0][ks], bhN[ks], aH0, 0, 0, 0);
            aH1 = __builtin_amdgcn_mfma_f32_16x16x32_bf16(ah[1][ks], bhN[ks], aH1, 0, 0, 0);
        }

        // epilogue for col-tile t
        int gcol = t * 16 + lr;
        float br = bih[gcol], bz = bih[DH + gcol], bn = bih[2 * DH + gcol];
        float cr = bhh[gcol], cz = bhh[DH + gcol], cn = bhh[2 * DH + gcol];
#pragma unroll
        for (int rt = 0; rt < 2; rt++) {
            f32x4 R = rt ? aR1 : aR0;
            f32x4 Z = rt ? aZ1 : aZ0;
            f32x4 I = rt ? aI1 : aI0;
            f32x4 Hn = rt ? aH1 : aH0;
#pragma unroll
            for (int j = 0; j < 4; j++) {
                int grow = row0 + rt * 16 + kg * 4 + j;
                if (grow < N) {
                    float hv = Hs[(size_t)grow * DH + gcol];
                    float r = 1.f / (1.f + __expf(-(R[j] + br + cr)));
                    float z = 1.f / (1.f + __expf(-(Z[j] + bz + cz)));
                    float n = tanhf(I[j] + bn + r * (Hn[j] + cn));
                    out[(size_t)grow * DH + gcol] = (1.f - z) * n + z * hv;
                }
            }
        }
    }
#undef WLOAD
}

extern "C" void kernel_launch(void* const* d_in, const int* in_sizes, int n_in,
                              void* d_out, int out_size, void* d_ws, size_t ws_size,
                              hipStream_t stream) {
    const float* x    = (const float*)d_in[0];
    const int*   ei   = (const int*)d_in[1];
    const float* h1   = (const float*)d_in[2];
    const float* h2   = (const float*)d_in[3];
    const float* h3   = (const float*)d_in[4];
    const float* g1w  = (const float*)d_in[5];
    const float* g1b  = (const float*)d_in[6];
    const float* g2w  = (const float*)d_in[7];
    const float* g2b  = (const float*)d_in[8];
    const float* wih1 = (const float*)d_in[9];
    const float* whh1 = (const float*)d_in[10];
    const float* bih1 = (const float*)d_in[11];
    const float* bhh1 = (const float*)d_in[12];
    const float* wih2 = (const float*)d_in[13];
    const float* whh2 = (const float*)d_in[14];
    const float* bih2 = (const float*)d_in[15];
    const float* bhh2 = (const float*)d_in[16];
    const float* wih3 = (const float*)d_in[17];
    const float* whh3 = (const float*)d_in[18];
    const float* bih3 = (const float*)d_in[19];
    const float* bhh3 = (const float*)d_in[20];

    int N = in_sizes[0] / DH;
    int E = in_sizes[1] / 2;
    int B = (N + SCB - 1) / SCB;
    int nstripes = (N + 127) / 128;
    int span = (N + 7) / 8;
    int chunkE = (E + NCHUNK - 1) / NCHUNK;

    char* wsp = (char*)d_ws;
    auto alloc = [&](size_t bytes) -> char* {
        char* p = wsp;
        wsp += (bytes + 63) & ~(size_t)63;
        return p;
    };
    unsigned* cnt = (unsigned*)alloc((size_t)N * 4);
    int* offs     = (int*)alloc(((size_t)N + 1) * 4);
    int* cur      = (int*)alloc((size_t)N * 4);
    float* dinv   = (float*)alloc((size_t)N * 4);
    unsigned* bsum= (unsigned*)alloc(((size_t)B + 1) * 4);
    int* csr_src  = (int*)alloc((size_t)E * 4);
    short* xwb    = (short*)alloc((size_t)N * DH * 2);   // bf16 xw table
    float* x2     = (float*)alloc((size_t)N * DH * 4);
    short* w1t    = (short*)alloc((size_t)DH * DH * 2);
    short* w2t    = (short*)alloc((size_t)DH * DH * 2);
    const int WN = 3 * DH * DH;      // 49152
    short* wbAll  = (short*)alloc((size_t)6 * WN * 2);
    short* wb[6];
    for (int i = 0; i < 6; i++) wb[i] = wbAll + (size_t)i * WN;

    float* out  = (float*)d_out;
    float* h1n  = out;
    float* h2n  = out + (size_t)N * DH;
    float* h3n  = out + 2 * (size_t)N * DH;

    // ---- weight prep (bf16) ----
    f2bf6_k<<<(6 * WN + 255) / 256, 256, 0, stream>>>(wih1, whh1, wih2, whh2, wih3, whh3, wbAll, WN);
    transpose_bf2_k<<<(2 * DH * DH + 255) / 256, 256, 0, stream>>>(g1w, g2w, w1t, w2t);

    // ---- CSR build (per call; deterministic), XCD-partitioned ----
    hipMemsetAsync(cnt, 0, (size_t)N * 4, stream);
    deg2_k<<<8 * NCHUNK, 256, 0, stream>>>(ei, E, cnt, span, chunkE);
    scan1_k<<<B, 256, 0, stream>>>(cnt, N, offs, bsum);
    scan2_k<<<1, 1024, 0, stream>>>(bsum, B);
    scan3_k<<<(N + 255) / 256, 256, 0, stream>>>(offs, cur, dinv, cnt, bsum, N, B);
    fill2_k<<<8 * NCHUNK, 256, 0, stream>>>(ei, E, cur, csr_src, span, chunkE);

    int gblocks = (N + 3) / 4;

    // ---- GCN layer 1 ----
    gemm_mfma_k<<<nstripes, 256, 0, stream>>>(x, w1t, xwb, N);
    gather_k<<<gblocks, 256, 0, stream>>>(csr_src, offs, dinv, (const unsigned*)xwb, g1b, x2, N);

    // ---- GCN layer 2 ----
    gemm_mfma_k<<<nstripes, 256, 0, stream>>>(x2, w2t, xwb, N);
    gather_k<<<gblocks, 256, 0, stream>>>(csr_src, offs, dinv, (const unsigned*)xwb, g2b, x2, N);

    // ---- GRU chain ----
    gru_mfma_k<<<nstripes, 256, 0, stream>>>(x2,  h1, wb[0], wb[1], bih1, bhh1, h1n, N);
    gru_mfma_k<<<nstripes, 256, 0, stream>>>(h1n, h2, wb[2], wb[3], bih2, bhh2, h2n, N);
    gru_mfma_k<<<nstripes, 256, 0, stream>>>(h2n, h3, wb[4], wb[5], bih3, bhh3, h3n, N);
}

// Round 10
// 727.509 us; speedup vs baseline: 1.5651x; 1.1371x over previous
//
#include <hip/hip_runtime.h>
#include <hip/hip_bf16.h>

#define DH 128          // feature dim (D_IN == H == 128)
#define SCB 1024        // scan elements per block
#define NCHUNK 256      // edge chunks for XCD-partitioned CSR build

typedef __attribute__((ext_vector_type(8))) short short8_t;
typedef __attribute__((ext_vector_type(4))) float f32x4;

static __device__ __forceinline__ short f2bf(float f) {
    union { float f; unsigned u; } v; v.f = f;
    unsigned r = v.u + 0x7fffu + ((v.u >> 16) & 1u);   // RNE
    return (short)(r >> 16);
}

static __device__ __forceinline__ float bf2f(unsigned short b) {
    union { unsigned u; float f; } v; v.u = ((unsigned)b) << 16;
    return v.f;
}

static __device__ __forceinline__ short8_t cvt8(const float* p) {
    float4 a0 = *(const float4*)p;
    float4 a1 = *(const float4*)(p + 4);
    short8_t t;
    t[0] = f2bf(a0.x); t[1] = f2bf(a0.y); t[2] = f2bf(a0.z); t[3] = f2bf(a0.w);
    t[4] = f2bf(a1.x); t[5] = f2bf(a1.y); t[6] = f2bf(a1.z); t[7] = f2bf(a1.w);
    return t;
}

// ---------------- degree histogram, XCD-partitioned ----------------
__global__ __launch_bounds__(256) void deg2_k(const int* __restrict__ ei, int E,
                                              unsigned* __restrict__ cnt, int span, int chunkE) {
    int r = blockIdx.x & 7;
    int c = blockIdx.x >> 3;
    int lo = r * span, hi = lo + span;
    long long e0 = (long long)c * chunkE;
    long long e1 = e0 + chunkE; if (e1 > E) e1 = E;
    for (long long e = e0 + threadIdx.x; e < e1; e += 256) {
        int d = ei[E + e];
        if (d >= lo && d < hi) atomicAdd(&cnt[d], 1u);
    }
}

// ---------------- 3-phase grid-parallel exclusive scan ----------------
__global__ __launch_bounds__(256) void scan1_k(const unsigned* __restrict__ cnt, int N,
                                               int* __restrict__ offs, unsigned* __restrict__ bsum) {
    __shared__ unsigned s[256];
    int t = threadIdx.x;
    int i0 = blockIdx.x * SCB + t * 4;
    unsigned v0 = (i0 + 0 < N) ? cnt[i0 + 0] : 0u;
    unsigned v1 = (i0 + 1 < N) ? cnt[i0 + 1] : 0u;
    unsigned v2 = (i0 + 2 < N) ? cnt[i0 + 2] : 0u;
    unsigned v3 = (i0 + 3 < N) ? cnt[i0 + 3] : 0u;
    unsigned ts = v0 + v1 + v2 + v3;
    s[t] = ts;
    __syncthreads();
    for (int off = 1; off < 256; off <<= 1) {
        unsigned u = (t >= off) ? s[t - off] : 0u;
        __syncthreads();
        s[t] += u;
        __syncthreads();
    }
    unsigned ex = s[t] - ts;
    if (i0 + 0 < N) offs[i0 + 0] = (int)ex;
    if (i0 + 1 < N) offs[i0 + 1] = (int)(ex + v0);
    if (i0 + 2 < N) offs[i0 + 2] = (int)(ex + v0 + v1);
    if (i0 + 3 < N) offs[i0 + 3] = (int)(ex + v0 + v1 + v2);
    if (t == 255) bsum[blockIdx.x] = s[255];
}

__global__ __launch_bounds__(1024) void scan2_k(unsigned* __restrict__ bsum, int B) {
    __shared__ unsigned s[1024];
    int t = threadIdx.x;
    unsigned v = (t < B) ? bsum[t] : 0u;
    s[t] = v;
    __syncthreads();
    for (int off = 1; off < 1024; off <<= 1) {
        unsigned u = (t >= off) ? s[t - off] : 0u;
        __syncthreads();
        s[t] += u;
        __syncthreads();
    }
    if (t < B) bsum[t] = s[t] - v;
    if (t == 0) bsum[B] = s[1023];
}

__global__ void scan3_k(int* __restrict__ offs, int* __restrict__ cur,
                        float* __restrict__ dinv, const unsigned* __restrict__ cnt,
                        const unsigned* __restrict__ bsum, int N, int B) {
    int i = blockIdx.x * 256 + threadIdx.x;
    if (i < N) {
        int v = offs[i] + (int)bsum[i >> 10];
        offs[i] = v;
        cur[i] = v;
        dinv[i] = rsqrtf((float)cnt[i] + 1.0f);
    }
    if (i == 0) offs[N] = (int)bsum[B];
}

// ---------------- CSR fill, XCD-partitioned ----------------
__global__ __launch_bounds__(256) void fill2_k(const int* __restrict__ ei, int E,
                                               int* __restrict__ cur, int* __restrict__ csr_src,
                                               int span, int chunkE) {
    int r = blockIdx.x & 7;
    int c = blockIdx.x >> 3;
    int lo = r * span, hi = lo + span;
    long long e0 = (long long)c * chunkE;
    long long e1 = e0 + chunkE; if (e1 > E) e1 = E;
    for (long long e = e0 + threadIdx.x; e < e1; e += 256) {
        int d = ei[E + e];
        if (d >= lo && d < hi) {
            int pos = atomicAdd(&cur[d], 1);
            csr_src[pos] = ei[e];
        }
    }
}

// ---------------- weight prep ----------------
__global__ void f2bf6_k(const float* __restrict__ s0, const float* __restrict__ s1,
                        const float* __restrict__ s2, const float* __restrict__ s3,
                        const float* __restrict__ s4, const float* __restrict__ s5,
                        short* __restrict__ dst, int WN) {
    int i = blockIdx.x * 256 + threadIdx.x;
    if (i >= 6 * WN) return;
    int b = i / WN, r = i - b * WN;
    const float* srcs[6] = {s0, s1, s2, s3, s4, s5};
    dst[i] = f2bf(srcs[b][r]);
}

__global__ void transpose_bf2_k(const float* __restrict__ sa, const float* __restrict__ sb,
                                short* __restrict__ da, short* __restrict__ db) {
    int i = blockIdx.x * 256 + threadIdx.x;   // 2*16384
    int m = i >> 14;
    int j = i & 16383;
    int c = j >> 7, k = j & 127;
    const float* s = m ? sb : sa;
    short* d = m ? db : da;
    d[j] = f2bf(s[k * DH + c]);
}

// ================= MFMA GEMM, register-streamed weights, depth-2 prefetch ===========
__global__ __launch_bounds__(256, 4) void gemm_mfma_k(const float* __restrict__ A,
                                                      const short* __restrict__ Wt,
                                                      short* __restrict__ C, int N) {
    int tid = threadIdx.x;
    int wave = tid >> 6, lane = tid & 63;
    int lr = lane & 15, kg = lane >> 4;

    int row0 = blockIdx.x * 128 + wave * 32;
    int ar0 = min(row0 + lr, N - 1);
    int ar1 = min(row0 + 16 + lr, N - 1);
    const float* a0p = A + (size_t)ar0 * DH;
    const float* a1p = A + (size_t)ar1 * DH;
    short8_t af[2][4];
#pragma unroll
    for (int ks = 0; ks < 4; ks++) {
        af[0][ks] = cvt8(a0p + ks * 32 + kg * 8);
        af[1][ks] = cvt8(a1p + ks * 32 + kg * 8);
    }

    short8_t bt[3][4];
#define GLOADW(slot, t) { \
    const short* wp = Wt + (size_t)((t) * 16 + lr) * DH + kg * 8; \
    bt[slot][0] = *(const short8_t*)(wp); \
    bt[slot][1] = *(const short8_t*)(wp + 32); \
    bt[slot][2] = *(const short8_t*)(wp + 64); \
    bt[slot][3] = *(const short8_t*)(wp + 96); }

    GLOADW(0, 0)
    GLOADW(1, 1)
#pragma unroll
    for (int t = 0; t < 8; t++) {
        if (t < 6) GLOADW((t + 2) % 3, t + 2)
        f32x4 acc0 = {0.f, 0.f, 0.f, 0.f};
        f32x4 acc1 = {0.f, 0.f, 0.f, 0.f};
#pragma unroll
        for (int ks = 0; ks < 4; ks++) {
            acc0 = __builtin_amdgcn_mfma_f32_16x16x32_bf16(af[0][ks], bt[t % 3][ks], acc0, 0, 0, 0);
            acc1 = __builtin_amdgcn_mfma_f32_16x16x32_bf16(af[1][ks], bt[t % 3][ks], acc1, 0, 0, 0);
        }
        int col = t * 16 + lr;
#pragma unroll
        for (int j = 0; j < 4; j++) {
            int g0 = row0 + kg * 4 + j;
            int g1 = row0 + 16 + kg * 4 + j;
            if (g0 < N) C[(size_t)g0 * DH + col] = f2bf(acc0[j]);
            if (g1 < N) C[(size_t)g1 * DH + col] = f2bf(acc1[j]);
        }
    }
#undef GLOADW
}

// ---------------- gather: bf16 xw table, fp32 output ----------------
__global__ __launch_bounds__(256) void gather_k(const int* __restrict__ csr_src,
                                                const int* __restrict__ offs,
                                                const float* __restrict__ dinv,
                                                const unsigned* __restrict__ xwb,  // bf16x2 per uint
                                                const float* __restrict__ bias,
                                                float* __restrict__ dest, int N) {
    int wid = blockIdx.x * 4 + (threadIdx.x >> 6);
    if (wid >= N) return;
    int lane = threadIdx.x & 63;
    int j = offs[wid];
    int end = offs[wid + 1];
    float dd = dinv[wid];
    float ax = 0.f, ay = 0.f;

    if (j < end) {
        int s = csr_src[j];
        float dv = dinv[s];
        for (; j + 1 < end; ++j) {
            int sn = csr_src[j + 1];
            float dvn = dinv[sn];
            unsigned v = xwb[(size_t)s * 64 + lane];
            float nrm = dd * dv;
            ax = fmaf(bf2f((unsigned short)(v & 0xffffu)), nrm, ax);
            ay = fmaf(bf2f((unsigned short)(v >> 16)), nrm, ay);
            s = sn; dv = dvn;
        }
        unsigned v = xwb[(size_t)s * 64 + lane];
        float nrm = dd * dv;
        ax = fmaf(bf2f((unsigned short)(v & 0xffffu)), nrm, ax);
        ay = fmaf(bf2f((unsigned short)(v >> 16)), nrm, ay);
    }

    unsigned xv = xwb[(size_t)wid * 64 + lane];
    float2 b2 = ((const float2*)bias)[lane];
    float sl = dd * dd;
    float ox = fmaxf(fmaf(bf2f((unsigned short)(xv & 0xffffu)), sl, ax) + b2.x, 0.f);
    float oy = fmaxf(fmaf(bf2f((unsigned short)(xv >> 16)), sl, ay) + b2.y, 0.f);
    float2 o; o.x = ox; o.y = oy;
    ((float2*)dest)[(size_t)wid * 64 + lane] = o;
}

// ================= fused MFMA GRU cell, LDS-staged ACTIVATIONS =====================
// 512 thr / 8 waves, 64 rows/block. X,H staged bf16 in LDS (32 KB, XOR-swizzled).
// Wave w owns output cols [16w,16w+16) for ALL 3 gates and all 64 rows:
// 24 weight-fragment L2 loads per wave per block (vs 192/32rows before),
// B-frags live in registers, A-frags via ds_read_b128.
__global__ __launch_bounds__(512, 1) void gru_mfma_k(const float* __restrict__ X,
                                                     const float* __restrict__ Hs,
                                                     const short* __restrict__ wih,
                                                     const short* __restrict__ whh,
                                                     const float* __restrict__ bih,
                                                     const float* __restrict__ bhh,
                                                     float* __restrict__ out, int N) {
    __shared__ short lds[2][64 * DH];    // [mat][row*128 + col], 16 KB each
    int tid = threadIdx.x;
    int row0 = blockIdx.x * 64;
    int wave = tid >> 6, lane = tid & 63;
    int lr = lane & 15, kg = lane >> 4;
    int c0 = wave * 16;

    // ---- issue per-wave weight loads first (24 x 16B, overlap with staging) ----
    short8_t bw[3][4], bu[3][4];   // [gate][ks]
#pragma unroll
    for (int g = 0; g < 3; g++) {
        const short* wi = wih + (size_t)(g * DH + c0 + lr) * DH + kg * 8;
        const short* wh = whh + (size_t)(g * DH + c0 + lr) * DH + kg * 8;
#pragma unroll
        for (int ks = 0; ks < 4; ks++) {
            bw[g][ks] = *(const short8_t*)(wi + ks * 32);
            bu[g][ks] = *(const short8_t*)(wh + ks * 32);
        }
    }

    // ---- stage X,H -> LDS bf16, swizzled: byte ^= (row&7)<<4 ----
    {
        int mat = tid >> 8;            // 0=X, 1=H
        int r = (tid & 255) >> 2;      // 0..63
        int q = tid & 3;               // 32-col chunk
        int grow = min(row0 + r, N - 1);
        const float* src = (mat ? Hs : X) + (size_t)grow * DH + q * 32;
        char* dst = (char*)&lds[mat][r * DH];
#pragma unroll
        for (int j = 0; j < 4; j++) {
            short8_t v = cvt8(src + j * 8);
            int boff = (q * 64 + j * 16) ^ ((r & 7) << 4);
            *(short8_t*)(dst + boff) = v;
        }
    }
    __syncthreads();

    // ---- compute: 4 row-tiles x (R,Z,N) x 4 ks ----
    f32x4 aR[4], aZ[4], aI[4], aH[4];
#pragma unroll
    for (int rt = 0; rt < 4; rt++) {
        aR[rt] = (f32x4){0,0,0,0}; aZ[rt] = (f32x4){0,0,0,0};
        aI[rt] = (f32x4){0,0,0,0}; aH[rt] = (f32x4){0,0,0,0};
    }

#pragma unroll
    for (int rt = 0; rt < 4; rt++) {
        int r = rt * 16 + lr;
        char* xrow = (char*)&lds[0][r * DH];
        char* hrow = (char*)&lds[1][r * DH];
        short8_t xa[4], ha[4];
#pragma unroll
        for (int ks = 0; ks < 4; ks++) {
            int boff = (ks * 64 + kg * 16) ^ ((r & 7) << 4);
            xa[ks] = *(short8_t*)(xrow + boff);
            ha[ks] = *(short8_t*)(hrow + boff);
        }
#pragma unroll
        for (int ks = 0; ks < 4; ks++) {
            aR[rt] = __builtin_amdgcn_mfma_f32_16x16x32_bf16(xa[ks], bw[0][ks], aR[rt], 0, 0, 0);
            aR[rt] = __builtin_amdgcn_mfma_f32_16x16x32_bf16(ha[ks], bu[0][ks], aR[rt], 0, 0, 0);
            aZ[rt] = __builtin_amdgcn_mfma_f32_16x16x32_bf16(xa[ks], bw[1][ks], aZ[rt], 0, 0, 0);
            aZ[rt] = __builtin_amdgcn_mfma_f32_16x16x32_bf16(ha[ks], bu[1][ks], aZ[rt], 0, 0, 0);
            aI[rt] = __builtin_amdgcn_mfma_f32_16x16x32_bf16(xa[ks], bw[2][ks], aI[rt], 0, 0, 0);
            aH[rt] = __builtin_amdgcn_mfma_f32_16x16x32_bf16(ha[ks], bu[2][ks], aH[rt], 0, 0, 0);
        }
    }

    // ---- epilogue: gates + blend (H fp32 from L2-warm global) ----
    int gcol = c0 + lr;
    float br = bih[gcol], bz = bih[DH + gcol], bn = bih[2 * DH + gcol];
    float cr = bhh[gcol], cz = bhh[DH + gcol], cn = bhh[2 * DH + gcol];
#pragma unroll
    for (int rt = 0; rt < 4; rt++) {
#pragma unroll
        for (int j = 0; j < 4; j++) {
            int grow = row0 + rt * 16 + kg * 4 + j;
            if (grow < N) {
                float hv = Hs[(size_t)grow * DH + gcol];
                float r = 1.f / (1.f + __expf(-(aR[rt][j] + br + cr)));
                float z = 1.f / (1.f + __expf(-(aZ[rt][j] + bz + cz)));
                float n = tanhf(aI[rt][j] + bn + r * (aH[rt][j] + cn));
                out[(size_t)grow * DH + gcol] = (1.f - z) * n + z * hv;
            }
        }
    }
}

extern "C" void kernel_launch(void* const* d_in, const int* in_sizes, int n_in,
                              void* d_out, int out_size, void* d_ws, size_t ws_size,
                              hipStream_t stream) {
    const float* x    = (const float*)d_in[0];
    const int*   ei   = (const int*)d_in[1];
    const float* h1   = (const float*)d_in[2];
    const float* h2   = (const float*)d_in[3];
    const float* h3   = (const float*)d_in[4];
    const float* g1w  = (const float*)d_in[5];
    const float* g1b  = (const float*)d_in[6];
    const float* g2w  = (const float*)d_in[7];
    const float* g2b  = (const float*)d_in[8];
    const float* wih1 = (const float*)d_in[9];
    const float* whh1 = (const float*)d_in[10];
    const float* bih1 = (const float*)d_in[11];
    const float* bhh1 = (const float*)d_in[12];
    const float* wih2 = (const float*)d_in[13];
    const float* whh2 = (const float*)d_in[14];
    const float* bih2 = (const float*)d_in[15];
    const float* bhh2 = (const float*)d_in[16];
    const float* wih3 = (const float*)d_in[17];
    const float* whh3 = (const float*)d_in[18];
    const float* bih3 = (const float*)d_in[19];
    const float* bhh3 = (const float*)d_in[20];

    int N = in_sizes[0] / DH;
    int E = in_sizes[1] / 2;
    int B = (N + SCB - 1) / SCB;
    int nstripes = (N + 127) / 128;
    int nblk64 = (N + 63) / 64;
    int span = (N + 7) / 8;
    int chunkE = (E + NCHUNK - 1) / NCHUNK;

    char* wsp = (char*)d_ws;
    auto alloc = [&](size_t bytes) -> char* {
        char* p = wsp;
        wsp += (bytes + 63) & ~(size_t)63;
        return p;
    };
    unsigned* cnt = (unsigned*)alloc((size_t)N * 4);
    int* offs     = (int*)alloc(((size_t)N + 1) * 4);
    int* cur      = (int*)alloc((size_t)N * 4);
    float* dinv   = (float*)alloc((size_t)N * 4);
    unsigned* bsum= (unsigned*)alloc(((size_t)B + 1) * 4);
    int* csr_src  = (int*)alloc((size_t)E * 4);
    short* xwb    = (short*)alloc((size_t)N * DH * 2);   // bf16 xw table
    float* x2     = (float*)alloc((size_t)N * DH * 4);
    short* w1t    = (short*)alloc((size_t)DH * DH * 2);
    short* w2t    = (short*)alloc((size_t)DH * DH * 2);
    const int WN = 3 * DH * DH;      // 49152
    short* wbAll  = (short*)alloc((size_t)6 * WN * 2);
    short* wb[6];
    for (int i = 0; i < 6; i++) wb[i] = wbAll + (size_t)i * WN;

    float* out  = (float*)d_out;
    float* h1n  = out;
    float* h2n  = out + (size_t)N * DH;
    float* h3n  = out + 2 * (size_t)N * DH;

    // ---- weight prep (bf16) ----
    f2bf6_k<<<(6 * WN + 255) / 256, 256, 0, stream>>>(wih1, whh1, wih2, whh2, wih3, whh3, wbAll, WN);
    transpose_bf2_k<<<(2 * DH * DH + 255) / 256, 256, 0, stream>>>(g1w, g2w, w1t, w2t);

    // ---- CSR build (per call; deterministic), XCD-partitioned ----
    hipMemsetAsync(cnt, 0, (size_t)N * 4, stream);
    deg2_k<<<8 * NCHUNK, 256, 0, stream>>>(ei, E, cnt, span, chunkE);
    scan1_k<<<B, 256, 0, stream>>>(cnt, N, offs, bsum);
    scan2_k<<<1, 1024, 0, stream>>>(bsum, B);
    scan3_k<<<(N + 255) / 256, 256, 0, stream>>>(offs, cur, dinv, cnt, bsum, N, B);
    fill2_k<<<8 * NCHUNK, 256, 0, stream>>>(ei, E, cur, csr_src, span, chunkE);

    int gblocks = (N + 3) / 4;

    // ---- GCN layer 1 ----
    gemm_mfma_k<<<nstripes, 256, 0, stream>>>(x, w1t, xwb, N);
    gather_k<<<gblocks, 256, 0, stream>>>(csr_src, offs, dinv, (const unsigned*)xwb, g1b, x2, N);

    // ---- GCN layer 2 ----
    gemm_mfma_k<<<nstripes, 256, 0, stream>>>(x2, w2t, xwb, N);
    gather_k<<<gblocks, 256, 0, stream>>>(csr_src, offs, dinv, (const unsigned*)xwb, g2b, x2, N);

    // ---- GRU chain ----
    gru_mfma_k<<<nblk64, 512, 0, stream>>>(x2,  h1, wb[0], wb[1], bih1, bhh1, h1n, N);
    gru_mfma_k<<<nblk64, 512, 0, stream>>>(h1n, h2, wb[2], wb[3], bih2, bhh2, h2n, N);
    gru_mfma_k<<<nblk64, 512, 0, stream>>>(h2n, h3, wb[4], wb[5], bih3, bhh3, h3n, N);
}

// Round 11
// 646.868 us; speedup vs baseline: 1.7602x; 1.1247x over previous
//
#include <hip/hip_runtime.h>
#include <hip/hip_bf16.h>

#define DH 128          // feature dim (D_IN == H == 128)
#define SCB 1024        // scan elements per block
#define NCHUNK 256      // edge chunks for XCD-partitioned CSR build

typedef __attribute__((ext_vector_type(8))) short short8_t;
typedef __attribute__((ext_vector_type(4))) float f32x4;

static __device__ __forceinline__ short f2bf(float f) {
    union { float f; unsigned u; } v; v.f = f;
    unsigned r = v.u + 0x7fffu + ((v.u >> 16) & 1u);   // RNE
    return (short)(r >> 16);
}

static __device__ __forceinline__ float bf2f(unsigned short b) {
    union { unsigned u; float f; } v; v.u = ((unsigned)b) << 16;
    return v.f;
}

static __device__ __forceinline__ short8_t cvt8(const float* p) {
    float4 a0 = *(const float4*)p;
    float4 a1 = *(const float4*)(p + 4);
    short8_t t;
    t[0] = f2bf(a0.x); t[1] = f2bf(a0.y); t[2] = f2bf(a0.z); t[3] = f2bf(a0.w);
    t[4] = f2bf(a1.x); t[5] = f2bf(a1.y); t[6] = f2bf(a1.z); t[7] = f2bf(a1.w);
    return t;
}

// ---------------- degree histogram, XCD-partitioned ----------------
__global__ __launch_bounds__(256) void deg2_k(const int* __restrict__ ei, int E,
                                              unsigned* __restrict__ cnt, int span, int chunkE) {
    int r = blockIdx.x & 7;
    int c = blockIdx.x >> 3;
    int lo = r * span, hi = lo + span;
    long long e0 = (long long)c * chunkE;
    long long e1 = e0 + chunkE; if (e1 > E) e1 = E;
    for (long long e = e0 + threadIdx.x; e < e1; e += 256) {
        int d = ei[E + e];
        if (d >= lo && d < hi) atomicAdd(&cnt[d], 1u);
    }
}

// ---------------- 3-phase grid-parallel exclusive scan ----------------
__global__ __launch_bounds__(256) void scan1_k(const unsigned* __restrict__ cnt, int N,
                                               int* __restrict__ offs, unsigned* __restrict__ bsum) {
    __shared__ unsigned s[256];
    int t = threadIdx.x;
    int i0 = blockIdx.x * SCB + t * 4;
    unsigned v0 = (i0 + 0 < N) ? cnt[i0 + 0] : 0u;
    unsigned v1 = (i0 + 1 < N) ? cnt[i0 + 1] : 0u;
    unsigned v2 = (i0 + 2 < N) ? cnt[i0 + 2] : 0u;
    unsigned v3 = (i0 + 3 < N) ? cnt[i0 + 3] : 0u;
    unsigned ts = v0 + v1 + v2 + v3;
    s[t] = ts;
    __syncthreads();
    for (int off = 1; off < 256; off <<= 1) {
        unsigned u = (t >= off) ? s[t - off] : 0u;
        __syncthreads();
        s[t] += u;
        __syncthreads();
    }
    unsigned ex = s[t] - ts;
    if (i0 + 0 < N) offs[i0 + 0] = (int)ex;
    if (i0 + 1 < N) offs[i0 + 1] = (int)(ex + v0);
    if (i0 + 2 < N) offs[i0 + 2] = (int)(ex + v0 + v1);
    if (i0 + 3 < N) offs[i0 + 3] = (int)(ex + v0 + v1 + v2);
    if (t == 255) bsum[blockIdx.x] = s[255];
}

__global__ __launch_bounds__(1024) void scan2_k(unsigned* __restrict__ bsum, int B) {
    __shared__ unsigned s[1024];
    int t = threadIdx.x;
    unsigned v = (t < B) ? bsum[t] : 0u;
    s[t] = v;
    __syncthreads();
    for (int off = 1; off < 1024; off <<= 1) {
        unsigned u = (t >= off) ? s[t - off] : 0u;
        __syncthreads();
        s[t] += u;
        __syncthreads();
    }
    if (t < B) bsum[t] = s[t] - v;
    if (t == 0) bsum[B] = s[1023];
}

__global__ void scan3_k(int* __restrict__ offs, int* __restrict__ cur,
                        float* __restrict__ dinv, const unsigned* __restrict__ cnt,
                        const unsigned* __restrict__ bsum, int N, int B) {
    int i = blockIdx.x * 256 + threadIdx.x;
    if (i < N) {
        int v = offs[i] + (int)bsum[i >> 10];
        offs[i] = v;
        cur[i] = v;
        dinv[i] = rsqrtf((float)cnt[i] + 1.0f);
    }
    if (i == 0) offs[N] = (int)bsum[B];
}

// ---------------- CSR fill, XCD-partitioned ----------------
__global__ __launch_bounds__(256) void fill2_k(const int* __restrict__ ei, int E,
                                               int* __restrict__ cur, int* __restrict__ csr_src,
                                               int span, int chunkE) {
    int r = blockIdx.x & 7;
    int c = blockIdx.x >> 3;
    int lo = r * span, hi = lo + span;
    long long e0 = (long long)c * chunkE;
    long long e1 = e0 + chunkE; if (e1 > E) e1 = E;
    for (long long e = e0 + threadIdx.x; e < e1; e += 256) {
        int d = ei[E + e];
        if (d >= lo && d < hi) {
            int pos = atomicAdd(&cur[d], 1);
            csr_src[pos] = ei[e];
        }
    }
}

// ---------------- weight prep ----------------
__global__ void f2bf6_k(const float* __restrict__ s0, const float* __restrict__ s1,
                        const float* __restrict__ s2, const float* __restrict__ s3,
                        const float* __restrict__ s4, const float* __restrict__ s5,
                        short* __restrict__ dst, int WN) {
    int i = blockIdx.x * 256 + threadIdx.x;
    if (i >= 6 * WN) return;
    int b = i / WN, r = i - b * WN;
    const float* srcs[6] = {s0, s1, s2, s3, s4, s5};
    dst[i] = f2bf(srcs[b][r]);
}

__global__ void transpose_bf2_k(const float* __restrict__ sa, const float* __restrict__ sb,
                                short* __restrict__ da, short* __restrict__ db) {
    int i = blockIdx.x * 256 + threadIdx.x;   // 2*16384
    int m = i >> 14;
    int j = i & 16383;
    int c = j >> 7, k = j & 127;
    const float* s = m ? sb : sa;
    short* d = m ? db : da;
    d[j] = f2bf(s[k * DH + c]);
}

// ================= MFMA GEMM -> pre-scaled bf16 table ===========
// xws[r][c] = bf16( (A @ Wt^T)[r][c] * dinv[r] )
__global__ __launch_bounds__(256, 4) void gemm_mfma_k(const float* __restrict__ A,
                                                      const short* __restrict__ Wt,
                                                      const float* __restrict__ dinv,
                                                      short* __restrict__ C, int N) {
    int tid = threadIdx.x;
    int wave = tid >> 6, lane = tid & 63;
    int lr = lane & 15, kg = lane >> 4;

    int row0 = blockIdx.x * 128 + wave * 32;
    int ar0 = min(row0 + lr, N - 1);
    int ar1 = min(row0 + 16 + lr, N - 1);
    const float* a0p = A + (size_t)ar0 * DH;
    const float* a1p = A + (size_t)ar1 * DH;
    short8_t af[2][4];
#pragma unroll
    for (int ks = 0; ks < 4; ks++) {
        af[0][ks] = cvt8(a0p + ks * 32 + kg * 8);
        af[1][ks] = cvt8(a1p + ks * 32 + kg * 8);
    }

    // per-lane output-row dinv (constant across col-tiles)
    float di0[4], di1[4];
#pragma unroll
    for (int j = 0; j < 4; j++) {
        di0[j] = dinv[min(row0 + kg * 4 + j, N - 1)];
        di1[j] = dinv[min(row0 + 16 + kg * 4 + j, N - 1)];
    }

    short8_t bt[3][4];
#define GLOADW(slot, t) { \
    const short* wp = Wt + (size_t)((t) * 16 + lr) * DH + kg * 8; \
    bt[slot][0] = *(const short8_t*)(wp); \
    bt[slot][1] = *(const short8_t*)(wp + 32); \
    bt[slot][2] = *(const short8_t*)(wp + 64); \
    bt[slot][3] = *(const short8_t*)(wp + 96); }

    GLOADW(0, 0)
    GLOADW(1, 1)
#pragma unroll
    for (int t = 0; t < 8; t++) {
        if (t < 6) GLOADW((t + 2) % 3, t + 2)
        f32x4 acc0 = {0.f, 0.f, 0.f, 0.f};
        f32x4 acc1 = {0.f, 0.f, 0.f, 0.f};
#pragma unroll
        for (int ks = 0; ks < 4; ks++) {
            acc0 = __builtin_amdgcn_mfma_f32_16x16x32_bf16(af[0][ks], bt[t % 3][ks], acc0, 0, 0, 0);
            acc1 = __builtin_amdgcn_mfma_f32_16x16x32_bf16(af[1][ks], bt[t % 3][ks], acc1, 0, 0, 0);
        }
        int col = t * 16 + lr;
#pragma unroll
        for (int j = 0; j < 4; j++) {
            int g0 = row0 + kg * 4 + j;
            int g1 = row0 + 16 + kg * 4 + j;
            if (g0 < N) C[(size_t)g0 * DH + col] = f2bf(acc0[j] * di0[j]);
            if (g1 < N) C[(size_t)g1 * DH + col] = f2bf(acc1[j] * di1[j]);
        }
    }
#undef GLOADW
}

// ---------------- gather: pre-scaled bf16 table, chunk-4 pipelined ----------------
// dest[d] = relu( dd * ( sum_e xws[src_e] + xws[d] ) + b )
__global__ __launch_bounds__(256) void gather_k(const int* __restrict__ csr_src,
                                                const int* __restrict__ offs,
                                                const float* __restrict__ dinv,
                                                const unsigned* __restrict__ xws,  // bf16x2 per uint
                                                const float* __restrict__ bias,
                                                float* __restrict__ dest, int N) {
    int wid = blockIdx.x * 4 + (threadIdx.x >> 6);
    if (wid >= N) return;
    int lane = threadIdx.x & 63;
    int j = offs[wid];
    int end = offs[wid + 1];
    float dd = dinv[wid];

    // self-loop contribution = own (pre-scaled) row
    unsigned xv = xws[(size_t)wid * 64 + lane];
    float ax = bf2f((unsigned short)(xv & 0xffffu));
    float ay = bf2f((unsigned short)(xv >> 16));

#define ACC(w) { ax += bf2f((unsigned short)((w) & 0xffffu)); \
                 ay += bf2f((unsigned short)((w) >> 16)); }

    if (j + 4 <= end) {
        int a0 = csr_src[j], a1 = csr_src[j + 1], a2 = csr_src[j + 2], a3 = csr_src[j + 3];
        j += 4;
        for (; j + 4 <= end; j += 4) {
            // 4 independent row loads in flight
            unsigned w0 = xws[(size_t)a0 * 64 + lane];
            unsigned w1 = xws[(size_t)a1 * 64 + lane];
            unsigned w2 = xws[(size_t)a2 * 64 + lane];
            unsigned w3 = xws[(size_t)a3 * 64 + lane];
            // prefetch next chunk's indices while rows are in flight
            a0 = csr_src[j]; a1 = csr_src[j + 1]; a2 = csr_src[j + 2]; a3 = csr_src[j + 3];
            ACC(w0) ACC(w1) ACC(w2) ACC(w3)
        }
        // drain current chunk
        unsigned w0 = xws[(size_t)a0 * 64 + lane];
        unsigned w1 = xws[(size_t)a1 * 64 + lane];
        unsigned w2 = xws[(size_t)a2 * 64 + lane];
        unsigned w3 = xws[(size_t)a3 * 64 + lane];
        ACC(w0) ACC(w1) ACC(w2) ACC(w3)
    }
    // tail 0..3
    for (; j < end; ++j) {
        unsigned w = xws[(size_t)csr_src[j] * 64 + lane];
        ACC(w)
    }
#undef ACC

    float2 b2 = ((const float2*)bias)[lane];
    float ox = fmaxf(fmaf(dd, ax, b2.x), 0.f);
    float oy = fmaxf(fmaf(dd, ay, b2.y), 0.f);
    float2 o; o.x = ox; o.y = oy;
    ((float2*)dest)[(size_t)wid * 64 + lane] = o;
}

// ================= fused MFMA GRU cell, LDS-staged ACTIVATIONS =====================
__global__ __launch_bounds__(512, 1) void gru_mfma_k(const float* __restrict__ X,
                                                     const float* __restrict__ Hs,
                                                     const short* __restrict__ wih,
                                                     const short* __restrict__ whh,
                                                     const float* __restrict__ bih,
                                                     const float* __restrict__ bhh,
                                                     float* __restrict__ out, int N) {
    __shared__ short lds[2][64 * DH];    // [mat][row*128 + col], 16 KB each
    int tid = threadIdx.x;
    int row0 = blockIdx.x * 64;
    int wave = tid >> 6, lane = tid & 63;
    int lr = lane & 15, kg = lane >> 4;
    int c0 = wave * 16;

    // ---- issue per-wave weight loads first (24 x 16B, overlap with staging) ----
    short8_t bw[3][4], bu[3][4];   // [gate][ks]
#pragma unroll
    for (int g = 0; g < 3; g++) {
        const short* wi = wih + (size_t)(g * DH + c0 + lr) * DH + kg * 8;
        const short* wh = whh + (size_t)(g * DH + c0 + lr) * DH + kg * 8;
#pragma unroll
        for (int ks = 0; ks < 4; ks++) {
            bw[g][ks] = *(const short8_t*)(wi + ks * 32);
            bu[g][ks] = *(const short8_t*)(wh + ks * 32);
        }
    }

    // ---- stage X,H -> LDS bf16, swizzled: byte ^= (row&7)<<4 ----
    {
        int mat = tid >> 8;            // 0=X, 1=H
        int r = (tid & 255) >> 2;      // 0..63
        int q = tid & 3;               // 32-col chunk
        int grow = min(row0 + r, N - 1);
        const float* src = (mat ? Hs : X) + (size_t)grow * DH + q * 32;
        char* dst = (char*)&lds[mat][r * DH];
#pragma unroll
        for (int j = 0; j < 4; j++) {
            short8_t v = cvt8(src + j * 8);
            int boff = (q * 64 + j * 16) ^ ((r & 7) << 4);
            *(short8_t*)(dst + boff) = v;
        }
    }
    __syncthreads();

    // ---- compute: 4 row-tiles x (R,Z,N) x 4 ks ----
    f32x4 aR[4], aZ[4], aI[4], aH[4];
#pragma unroll
    for (int rt = 0; rt < 4; rt++) {
        aR[rt] = (f32x4){0,0,0,0}; aZ[rt] = (f32x4){0,0,0,0};
        aI[rt] = (f32x4){0,0,0,0}; aH[rt] = (f32x4){0,0,0,0};
    }

#pragma unroll
    for (int rt = 0; rt < 4; rt++) {
        int r = rt * 16 + lr;
        char* xrow = (char*)&lds[0][r * DH];
        char* hrow = (char*)&lds[1][r * DH];
        short8_t xa[4], ha[4];
#pragma unroll
        for (int ks = 0; ks < 4; ks++) {
            int boff = (ks * 64 + kg * 16) ^ ((r & 7) << 4);
            xa[ks] = *(short8_t*)(xrow + boff);
            ha[ks] = *(short8_t*)(hrow + boff);
        }
#pragma unroll
        for (int ks = 0; ks < 4; ks++) {
            aR[rt] = __builtin_amdgcn_mfma_f32_16x16x32_bf16(xa[ks], bw[0][ks], aR[rt], 0, 0, 0);
            aR[rt] = __builtin_amdgcn_mfma_f32_16x16x32_bf16(ha[ks], bu[0][ks], aR[rt], 0, 0, 0);
            aZ[rt] = __builtin_amdgcn_mfma_f32_16x16x32_bf16(xa[ks], bw[1][ks], aZ[rt], 0, 0, 0);
            aZ[rt] = __builtin_amdgcn_mfma_f32_16x16x32_bf16(ha[ks], bu[1][ks], aZ[rt], 0, 0, 0);
            aI[rt] = __builtin_amdgcn_mfma_f32_16x16x32_bf16(xa[ks], bw[2][ks], aI[rt], 0, 0, 0);
            aH[rt] = __builtin_amdgcn_mfma_f32_16x16x32_bf16(ha[ks], bu[2][ks], aH[rt], 0, 0, 0);
        }
    }

    // ---- epilogue: gates + blend (H fp32 from L2-warm global) ----
    int gcol = c0 + lr;
    float br = bih[gcol], bz = bih[DH + gcol], bn = bih[2 * DH + gcol];
    float cr = bhh[gcol], cz = bhh[DH + gcol], cn = bhh[2 * DH + gcol];
#pragma unroll
    for (int rt = 0; rt < 4; rt++) {
#pragma unroll
        for (int j = 0; j < 4; j++) {
            int grow = row0 + rt * 16 + kg * 4 + j;
            if (grow < N) {
                float hv = Hs[(size_t)grow * DH + gcol];
                float r = 1.f / (1.f + __expf(-(aR[rt][j] + br + cr)));
                float z = 1.f / (1.f + __expf(-(aZ[rt][j] + bz + cz)));
                float n = tanhf(aI[rt][j] + bn + r * (aH[rt][j] + cn));
                out[(size_t)grow * DH + gcol] = (1.f - z) * n + z * hv;
            }
        }
    }
}

extern "C" void kernel_launch(void* const* d_in, const int* in_sizes, int n_in,
                              void* d_out, int out_size, void* d_ws, size_t ws_size,
                              hipStream_t stream) {
    const float* x    = (const float*)d_in[0];
    const int*   ei   = (const int*)d_in[1];
    const float* h1   = (const float*)d_in[2];
    const float* h2   = (const float*)d_in[3];
    const float* h3   = (const float*)d_in[4];
    const float* g1w  = (const float*)d_in[5];
    const float* g1b  = (const float*)d_in[6];
    const float* g2w  = (const float*)d_in[7];
    const float* g2b  = (const float*)d_in[8];
    const float* wih1 = (const float*)d_in[9];
    const float* whh1 = (const float*)d_in[10];
    const float* bih1 = (const float*)d_in[11];
    const float* bhh1 = (const float*)d_in[12];
    const float* wih2 = (const float*)d_in[13];
    const float* whh2 = (const float*)d_in[14];
    const float* bih2 = (const float*)d_in[15];
    const float* bhh2 = (const float*)d_in[16];
    const float* wih3 = (const float*)d_in[17];
    const float* whh3 = (const float*)d_in[18];
    const float* bih3 = (const float*)d_in[19];
    const float* bhh3 = (const float*)d_in[20];

    int N = in_sizes[0] / DH;
    int E = in_sizes[1] / 2;
    int B = (N + SCB - 1) / SCB;
    int nstripes = (N + 127) / 128;
    int nblk64 = (N + 63) / 64;
    int span = (N + 7) / 8;
    int chunkE = (E + NCHUNK - 1) / NCHUNK;

    char* wsp = (char*)d_ws;
    auto alloc = [&](size_t bytes) -> char* {
        char* p = wsp;
        wsp += (bytes + 63) & ~(size_t)63;
        return p;
    };
    unsigned* cnt = (unsigned*)alloc((size_t)N * 4);
    int* offs     = (int*)alloc(((size_t)N + 1) * 4);
    int* cur      = (int*)alloc((size_t)N * 4);
    float* dinv   = (float*)alloc((size_t)N * 4);
    unsigned* bsum= (unsigned*)alloc(((size_t)B + 1) * 4);
    int* csr_src  = (int*)alloc((size_t)E * 4);
    short* xwb    = (short*)alloc((size_t)N * DH * 2);   // pre-scaled bf16 table
    float* x2     = (float*)alloc((size_t)N * DH * 4);
    short* w1t    = (short*)alloc((size_t)DH * DH * 2);
    short* w2t    = (short*)alloc((size_t)DH * DH * 2);
    const int WN = 3 * DH * DH;      // 49152
    short* wbAll  = (short*)alloc((size_t)6 * WN * 2);
    short* wb[6];
    for (int i = 0; i < 6; i++) wb[i] = wbAll + (size_t)i * WN;

    float* out  = (float*)d_out;
    float* h1n  = out;
    float* h2n  = out + (size_t)N * DH;
    float* h3n  = out + 2 * (size_t)N * DH;

    // ---- weight prep (bf16) ----
    f2bf6_k<<<(6 * WN + 255) / 256, 256, 0, stream>>>(wih1, whh1, wih2, whh2, wih3, whh3, wbAll, WN);
    transpose_bf2_k<<<(2 * DH * DH + 255) / 256, 256, 0, stream>>>(g1w, g2w, w1t, w2t);

    // ---- CSR build (per call; deterministic), XCD-partitioned ----
    hipMemsetAsync(cnt, 0, (size_t)N * 4, stream);
    deg2_k<<<8 * NCHUNK, 256, 0, stream>>>(ei, E, cnt, span, chunkE);
    scan1_k<<<B, 256, 0, stream>>>(cnt, N, offs, bsum);
    scan2_k<<<1, 1024, 0, stream>>>(bsum, B);
    scan3_k<<<(N + 255) / 256, 256, 0, stream>>>(offs, cur, dinv, cnt, bsum, N, B);
    fill2_k<<<8 * NCHUNK, 256, 0, stream>>>(ei, E, cur, csr_src, span, chunkE);

    int gblocks = (N + 3) / 4;

    // ---- GCN layer 1 ----
    gemm_mfma_k<<<nstripes, 256, 0, stream>>>(x, w1t, dinv, xwb, N);
    gather_k<<<gblocks, 256, 0, stream>>>(csr_src, offs, dinv, (const unsigned*)xwb, g1b, x2, N);

    // ---- GCN layer 2 ----
    gemm_mfma_k<<<nstripes, 256, 0, stream>>>(x2, w2t, dinv, xwb, N);
    gather_k<<<gblocks, 256, 0, stream>>>(csr_src, offs, dinv, (const unsigned*)xwb, g2b, x2, N);

    // ---- GRU chain ----
    gru_mfma_k<<<nblk64, 512, 0, stream>>>(x2,  h1, wb[0], wb[1], bih1, bhh1, h1n, N);
    gru_mfma_k<<<nblk64, 512, 0, stream>>>(h1n, h2, wb[2], wb[3], bih2, bhh2, h2n, N);
    gru_mfma_k<<<nblk64, 512, 0, stream>>>(h2n, h3, wb[4], wb[5], bih3, bhh3, h3n, N);
}

// Round 12
// 575.509 us; speedup vs baseline: 1.9784x; 1.1240x over previous
//
#include <hip/hip_runtime.h>
#include <hip/hip_bf16.h>

#define DH 128          // feature dim (D_IN == H == 128)
#define SCB 1024        // scan elements per block
#define NCHUNK 256      // edge chunks for XCD-partitioned CSR build

typedef __attribute__((ext_vector_type(8))) short short8_t;
typedef __attribute__((ext_vector_type(4))) float f32x4;

static __device__ __forceinline__ short f2bf(float f) {
    union { float f; unsigned u; } v; v.f = f;
    unsigned r = v.u + 0x7fffu + ((v.u >> 16) & 1u);   // RNE
    return (short)(r >> 16);
}

static __device__ __forceinline__ float bf2f(unsigned short b) {
    union { unsigned u; float f; } v; v.u = ((unsigned)b) << 16;
    return v.f;
}

static __device__ __forceinline__ short8_t cvt8(const float* p) {
    float4 a0 = *(const float4*)p;
    float4 a1 = *(const float4*)(p + 4);
    short8_t t;
    t[0] = f2bf(a0.x); t[1] = f2bf(a0.y); t[2] = f2bf(a0.z); t[3] = f2bf(a0.w);
    t[4] = f2bf(a1.x); t[5] = f2bf(a1.y); t[6] = f2bf(a1.z); t[7] = f2bf(a1.w);
    return t;
}

static __device__ __forceinline__ float sigm(float x) {
    return __builtin_amdgcn_rcpf(1.f + __expf(-x));
}
static __device__ __forceinline__ float tanh_f(float x) {
    // tanh(x) = 1 - 2/(exp(2x)+1); saturates correctly for |x| large
    return 1.f - 2.f * __builtin_amdgcn_rcpf(__expf(2.f * x) + 1.f);
}

// ---------------- degree histogram, XCD-partitioned ----------------
__global__ __launch_bounds__(256) void deg2_k(const int* __restrict__ ei, int E,
                                              unsigned* __restrict__ cnt, int span, int chunkE) {
    int r = blockIdx.x & 7;
    int c = blockIdx.x >> 3;
    int lo = r * span, hi = lo + span;
    long long e0 = (long long)c * chunkE;
    long long e1 = e0 + chunkE; if (e1 > E) e1 = E;
    for (long long e = e0 + threadIdx.x; e < e1; e += 256) {
        int d = ei[E + e];
        if (d >= lo && d < hi) atomicAdd(&cnt[d], 1u);
    }
}

// ---------------- 3-phase grid-parallel exclusive scan ----------------
__global__ __launch_bounds__(256) void scan1_k(const unsigned* __restrict__ cnt, int N,
                                               int* __restrict__ offs, unsigned* __restrict__ bsum) {
    __shared__ unsigned s[256];
    int t = threadIdx.x;
    int i0 = blockIdx.x * SCB + t * 4;
    unsigned v0 = (i0 + 0 < N) ? cnt[i0 + 0] : 0u;
    unsigned v1 = (i0 + 1 < N) ? cnt[i0 + 1] : 0u;
    unsigned v2 = (i0 + 2 < N) ? cnt[i0 + 2] : 0u;
    unsigned v3 = (i0 + 3 < N) ? cnt[i0 + 3] : 0u;
    unsigned ts = v0 + v1 + v2 + v3;
    s[t] = ts;
    __syncthreads();
    for (int off = 1; off < 256; off <<= 1) {
        unsigned u = (t >= off) ? s[t - off] : 0u;
        __syncthreads();
        s[t] += u;
        __syncthreads();
    }
    unsigned ex = s[t] - ts;
    if (i0 + 0 < N) offs[i0 + 0] = (int)ex;
    if (i0 + 1 < N) offs[i0 + 1] = (int)(ex + v0);
    if (i0 + 2 < N) offs[i0 + 2] = (int)(ex + v0 + v1);
    if (i0 + 3 < N) offs[i0 + 3] = (int)(ex + v0 + v1 + v2);
    if (t == 255) bsum[blockIdx.x] = s[255];
}

__global__ __launch_bounds__(1024) void scan2_k(unsigned* __restrict__ bsum, int B) {
    __shared__ unsigned s[1024];
    int t = threadIdx.x;
    unsigned v = (t < B) ? bsum[t] : 0u;
    s[t] = v;
    __syncthreads();
    for (int off = 1; off < 1024; off <<= 1) {
        unsigned u = (t >= off) ? s[t - off] : 0u;
        __syncthreads();
        s[t] += u;
        __syncthreads();
    }
    if (t < B) bsum[t] = s[t] - v;
    if (t == 0) bsum[B] = s[1023];
}

__global__ void scan3_k(int* __restrict__ offs, int* __restrict__ cur,
                        float* __restrict__ dinv, const unsigned* __restrict__ cnt,
                        const unsigned* __restrict__ bsum, int N, int B) {
    int i = blockIdx.x * 256 + threadIdx.x;
    if (i < N) {
        int v = offs[i] + (int)bsum[i >> 10];
        offs[i] = v;
        cur[i] = v;
        dinv[i] = rsqrtf((float)cnt[i] + 1.0f);
    }
    if (i == 0) offs[N] = (int)bsum[B];
}

// ---------------- CSR fill, XCD-partitioned ----------------
__global__ __launch_bounds__(256) void fill2_k(const int* __restrict__ ei, int E,
                                               int* __restrict__ cur, int* __restrict__ csr_src,
                                               int span, int chunkE) {
    int r = blockIdx.x & 7;
    int c = blockIdx.x >> 3;
    int lo = r * span, hi = lo + span;
    long long e0 = (long long)c * chunkE;
    long long e1 = e0 + chunkE; if (e1 > E) e1 = E;
    for (long long e = e0 + threadIdx.x; e < e1; e += 256) {
        int d = ei[E + e];
        if (d >= lo && d < hi) {
            int pos = atomicAdd(&cur[d], 1);
            csr_src[pos] = ei[e];
        }
    }
}

// ---------------- weight prep ----------------
__global__ void f2bf6_k(const float* __restrict__ s0, const float* __restrict__ s1,
                        const float* __restrict__ s2, const float* __restrict__ s3,
                        const float* __restrict__ s4, const float* __restrict__ s5,
                        short* __restrict__ dst, int WN) {
    int i = blockIdx.x * 256 + threadIdx.x;
    if (i >= 6 * WN) return;
    int b = i / WN, r = i - b * WN;
    const float* srcs[6] = {s0, s1, s2, s3, s4, s5};
    dst[i] = f2bf(srcs[b][r]);
}

__global__ void transpose_bf2_k(const float* __restrict__ sa, const float* __restrict__ sb,
                                short* __restrict__ da, short* __restrict__ db) {
    int i = blockIdx.x * 256 + threadIdx.x;   // 2*16384
    int m = i >> 14;
    int j = i & 16383;
    int c = j >> 7, k = j & 127;
    const float* s = m ? sb : sa;
    short* d = m ? db : da;
    d[j] = f2bf(s[k * DH + c]);
}

// ================= MFMA GEMM -> pre-scaled bf16 table ===========
// xws[r][c] = bf16( (A @ Wt^T)[r][c] * dinv[r] )
__global__ __launch_bounds__(256, 4) void gemm_mfma_k(const float* __restrict__ A,
                                                      const short* __restrict__ Wt,
                                                      const float* __restrict__ dinv,
                                                      short* __restrict__ C, int N) {
    int tid = threadIdx.x;
    int wave = tid >> 6, lane = tid & 63;
    int lr = lane & 15, kg = lane >> 4;

    int row0 = blockIdx.x * 128 + wave * 32;
    int ar0 = min(row0 + lr, N - 1);
    int ar1 = min(row0 + 16 + lr, N - 1);
    const float* a0p = A + (size_t)ar0 * DH;
    const float* a1p = A + (size_t)ar1 * DH;
    short8_t af[2][4];
#pragma unroll
    for (int ks = 0; ks < 4; ks++) {
        af[0][ks] = cvt8(a0p + ks * 32 + kg * 8);
        af[1][ks] = cvt8(a1p + ks * 32 + kg * 8);
    }

    float di0[4], di1[4];
#pragma unroll
    for (int j = 0; j < 4; j++) {
        di0[j] = dinv[min(row0 + kg * 4 + j, N - 1)];
        di1[j] = dinv[min(row0 + 16 + kg * 4 + j, N - 1)];
    }

    short8_t bt[3][4];
#define GLOADW(slot, t) { \
    const short* wp = Wt + (size_t)((t) * 16 + lr) * DH + kg * 8; \
    bt[slot][0] = *(const short8_t*)(wp); \
    bt[slot][1] = *(const short8_t*)(wp + 32); \
    bt[slot][2] = *(const short8_t*)(wp + 64); \
    bt[slot][3] = *(const short8_t*)(wp + 96); }

    GLOADW(0, 0)
    GLOADW(1, 1)
#pragma unroll
    for (int t = 0; t < 8; t++) {
        if (t < 6) GLOADW((t + 2) % 3, t + 2)
        f32x4 acc0 = {0.f, 0.f, 0.f, 0.f};
        f32x4 acc1 = {0.f, 0.f, 0.f, 0.f};
#pragma unroll
        for (int ks = 0; ks < 4; ks++) {
            acc0 = __builtin_amdgcn_mfma_f32_16x16x32_bf16(af[0][ks], bt[t % 3][ks], acc0, 0, 0, 0);
            acc1 = __builtin_amdgcn_mfma_f32_16x16x32_bf16(af[1][ks], bt[t % 3][ks], acc1, 0, 0, 0);
        }
        int col = t * 16 + lr;
#pragma unroll
        for (int j = 0; j < 4; j++) {
            int g0 = row0 + kg * 4 + j;
            int g1 = row0 + 16 + kg * 4 + j;
            if (g0 < N) C[(size_t)g0 * DH + col] = f2bf(acc0[j] * di0[j]);
            if (g1 < N) C[(size_t)g1 * DH + col] = f2bf(acc1[j] * di1[j]);
        }
    }
#undef GLOADW
}

// ---------------- gather: pre-scaled bf16 table, chunk-4 pipelined ----------------
__global__ __launch_bounds__(256) void gather_k(const int* __restrict__ csr_src,
                                                const int* __restrict__ offs,
                                                const float* __restrict__ dinv,
                                                const unsigned* __restrict__ xws,  // bf16x2 per uint
                                                const float* __restrict__ bias,
                                                float* __restrict__ dest, int N) {
    int wid = blockIdx.x * 4 + (threadIdx.x >> 6);
    if (wid >= N) return;
    int lane = threadIdx.x & 63;
    int j = offs[wid];
    int end = offs[wid + 1];
    float dd = dinv[wid];

    unsigned xv = xws[(size_t)wid * 64 + lane];
    float ax = bf2f((unsigned short)(xv & 0xffffu));
    float ay = bf2f((unsigned short)(xv >> 16));

#define ACC(w) { ax += bf2f((unsigned short)((w) & 0xffffu)); \
                 ay += bf2f((unsigned short)((w) >> 16)); }

    if (j + 4 <= end) {
        int a0 = csr_src[j], a1 = csr_src[j + 1], a2 = csr_src[j + 2], a3 = csr_src[j + 3];
        j += 4;
        for (; j + 4 <= end; j += 4) {
            unsigned w0 = xws[(size_t)a0 * 64 + lane];
            unsigned w1 = xws[(size_t)a1 * 64 + lane];
            unsigned w2 = xws[(size_t)a2 * 64 + lane];
            unsigned w3 = xws[(size_t)a3 * 64 + lane];
            a0 = csr_src[j]; a1 = csr_src[j + 1]; a2 = csr_src[j + 2]; a3 = csr_src[j + 3];
            ACC(w0) ACC(w1) ACC(w2) ACC(w3)
        }
        unsigned w0 = xws[(size_t)a0 * 64 + lane];
        unsigned w1 = xws[(size_t)a1 * 64 + lane];
        unsigned w2 = xws[(size_t)a2 * 64 + lane];
        unsigned w3 = xws[(size_t)a3 * 64 + lane];
        ACC(w0) ACC(w1) ACC(w2) ACC(w3)
    }
    for (; j < end; ++j) {
        unsigned w = xws[(size_t)csr_src[j] * 64 + lane];
        ACC(w)
    }
#undef ACC

    float2 b2 = ((const float2*)bias)[lane];
    float ox = fmaxf(fmaf(dd, ax, b2.x), 0.f);
    float oy = fmaxf(fmaf(dd, ay, b2.y), 0.f);
    float2 o; o.x = ox; o.y = oy;
    ((float2*)dest)[(size_t)wid * 64 + lane] = o;
}

// ================= FUSED 3x GRU cell chain, LDS-resident activations ===============
// 512 thr / 8 waves, 64 rows/block, wave owns 16 output cols for all 3 gates.
// lds[0] = current cell input X (bf16, swizzled), lds[1] = current cell hidden H.
// After cell c: h_next written back to lds[0] from registers; H_{c+2} staged
// from global into lds[1]. hv for the blend is read from lds[1] (bf16).
__global__ __launch_bounds__(512, 1) void gru3_mfma_k(
        const float* __restrict__ X, const float* __restrict__ H1,
        const float* __restrict__ H2, const float* __restrict__ H3,
        const short* __restrict__ w1i, const short* __restrict__ w1h,
        const short* __restrict__ w2i, const short* __restrict__ w2h,
        const short* __restrict__ w3i, const short* __restrict__ w3h,
        const float* __restrict__ bi1, const float* __restrict__ bh1,
        const float* __restrict__ bi2, const float* __restrict__ bh2,
        const float* __restrict__ bi3, const float* __restrict__ bh3,
        float* __restrict__ o1, float* __restrict__ o2, float* __restrict__ o3,
        int N) {
    __shared__ short lds[2][64 * DH];    // 32 KB
    int tid = threadIdx.x;
    int row0 = blockIdx.x * 64;
    int wave = tid >> 6, lane = tid & 63;
    int lr = lane & 15, kg = lane >> 4;
    int c0 = wave * 16;

    const short* wihs[3] = {w1i, w2i, w3i};
    const short* whhs[3] = {w1h, w2h, w3h};
    const float* bihs[3] = {bi1, bi2, bi3};
    const float* bhhs[3] = {bh1, bh2, bh3};
    const float* hnexts[2] = {H2, H3};
    float* outs[3] = {o1, o2, o3};

    short8_t bw[3][4], bu[3][4];   // weight frags for CURRENT cell
#define WLOADALL(wih_, whh_) { \
    _Pragma("unroll") \
    for (int g = 0; g < 3; g++) { \
        const short* wi = (wih_) + (size_t)(g * DH + c0 + lr) * DH + kg * 8; \
        const short* wh = (whh_) + (size_t)(g * DH + c0 + lr) * DH + kg * 8; \
        _Pragma("unroll") \
        for (int ks = 0; ks < 4; ks++) { \
            bw[g][ks] = *(const short8_t*)(wi + ks * 32); \
            bu[g][ks] = *(const short8_t*)(wh + ks * 32); \
        } \
    } }

    WLOADALL(w1i, w1h)

    // ---- initial stage: X -> lds[0], H1 -> lds[1] (bf16, swizzled) ----
    {
        int mat = tid >> 8;            // 0=X, 1=H1
        int r = (tid & 255) >> 2;      // 0..63
        int q = tid & 3;               // 32-col chunk
        int grow = min(row0 + r, N - 1);
        const float* src = (mat ? H1 : X) + (size_t)grow * DH + q * 32;
        char* dst = (char*)&lds[mat][r * DH];
#pragma unroll
        for (int j = 0; j < 4; j++) {
            short8_t v = cvt8(src + j * 8);
            int boff = (q * 64 + j * 16) ^ ((r & 7) << 4);
            *(short8_t*)(dst + boff) = v;
        }
    }
    __syncthreads();

    int gcol = c0 + lr;
    int colb = gcol * 2;               // byte offset of this lane's column

#pragma unroll
    for (int cell = 0; cell < 3; cell++) {
        // ---- MFMA phase ----
        f32x4 aR[4], aZ[4], aI[4], aH[4];
#pragma unroll
        for (int rt = 0; rt < 4; rt++) {
            aR[rt] = (f32x4){0,0,0,0}; aZ[rt] = (f32x4){0,0,0,0};
            aI[rt] = (f32x4){0,0,0,0}; aH[rt] = (f32x4){0,0,0,0};
        }
#pragma unroll
        for (int rt = 0; rt < 4; rt++) {
            int r = rt * 16 + lr;
            char* xrow = (char*)&lds[0][r * DH];
            char* hrow = (char*)&lds[1][r * DH];
            short8_t xa[4], ha[4];
#pragma unroll
            for (int ks = 0; ks < 4; ks++) {
                int boff = (ks * 64 + kg * 16) ^ ((r & 7) << 4);
                xa[ks] = *(short8_t*)(xrow + boff);
                ha[ks] = *(short8_t*)(hrow + boff);
            }
#pragma unroll
            for (int ks = 0; ks < 4; ks++) {
                aR[rt] = __builtin_amdgcn_mfma_f32_16x16x32_bf16(xa[ks], bw[0][ks], aR[rt], 0, 0, 0);
                aR[rt] = __builtin_amdgcn_mfma_f32_16x16x32_bf16(ha[ks], bu[0][ks], aR[rt], 0, 0, 0);
                aZ[rt] = __builtin_amdgcn_mfma_f32_16x16x32_bf16(xa[ks], bw[1][ks], aZ[rt], 0, 0, 0);
                aZ[rt] = __builtin_amdgcn_mfma_f32_16x16x32_bf16(ha[ks], bu[1][ks], aZ[rt], 0, 0, 0);
                aI[rt] = __builtin_amdgcn_mfma_f32_16x16x32_bf16(xa[ks], bw[2][ks], aI[rt], 0, 0, 0);
                aH[rt] = __builtin_amdgcn_mfma_f32_16x16x32_bf16(ha[ks], bu[2][ks], aH[rt], 0, 0, 0);
            }
        }

        // ---- epilogue (reads hv from lds[1], pre-barrier) ----
        const float* bih = bihs[cell];
        const float* bhh = bhhs[cell];
        float br = bih[gcol], bz = bih[DH + gcol], bn = bih[2 * DH + gcol];
        float cr = bhh[gcol], cz = bhh[DH + gcol], cn = bhh[2 * DH + gcol];
        float* outp = outs[cell];
        short hb[4][4];                 // bf16 h_next for LDS write-back
#pragma unroll
        for (int rt = 0; rt < 4; rt++) {
#pragma unroll
            for (int j = 0; j < 4; j++) {
                int r = rt * 16 + kg * 4 + j;
                float hv = bf2f(*(unsigned short*)((char*)&lds[1][r * DH] + (colb ^ ((r & 7) << 4))));
                float rr = sigm(aR[rt][j] + br + cr);
                float zz = sigm(aZ[rt][j] + bz + cz);
                float nn = tanh_f(aI[rt][j] + bn + rr * (aH[rt][j] + cn));
                float ov = (1.f - zz) * nn + zz * hv;
                int grow = row0 + r;
                if (grow < N) outp[(size_t)grow * DH + gcol] = ov;
                hb[rt][j] = f2bf(ov);
            }
        }

        // ---- prefetch next cell's weights (covered by staging + barrier drain) ----
        if (cell < 2) {
            WLOADALL(wihs[cell + 1], whhs[cell + 1])
        }

        __syncthreads();   // everyone done READING lds[0]/lds[1]

        if (cell < 2) {
            // write h_next (bf16) into lds[0] — same swizzle the frag reads use
#pragma unroll
            for (int rt = 0; rt < 4; rt++) {
#pragma unroll
                for (int j = 0; j < 4; j++) {
                    int r = rt * 16 + kg * 4 + j;
                    *(short*)((char*)&lds[0][r * DH] + (colb ^ ((r & 7) << 4))) = hb[rt][j];
                }
            }
            // stage H_{cell+2} -> lds[1]
            {
                int r = tid >> 3;          // 0..63
                int q = tid & 7;           // 16-col chunk
                int grow = min(row0 + r, N - 1);
                const float* src = hnexts[cell] + (size_t)grow * DH + q * 16;
                char* dst = (char*)&lds[1][r * DH];
#pragma unroll
                for (int j = 0; j < 2; j++) {
                    short8_t v = cvt8(src + j * 8);
                    int boff = (q * 32 + j * 16) ^ ((r & 7) << 4);
                    *(short8_t*)(dst + boff) = v;
                }
            }
            __syncthreads();
        }
    }
#undef WLOADALL
}

extern "C" void kernel_launch(void* const* d_in, const int* in_sizes, int n_in,
                              void* d_out, int out_size, void* d_ws, size_t ws_size,
                              hipStream_t stream) {
    const float* x    = (const float*)d_in[0];
    const int*   ei   = (const int*)d_in[1];
    const float* h1   = (const float*)d_in[2];
    const float* h2   = (const float*)d_in[3];
    const float* h3   = (const float*)d_in[4];
    const float* g1w  = (const float*)d_in[5];
    const float* g1b  = (const float*)d_in[6];
    const float* g2w  = (const float*)d_in[7];
    const float* g2b  = (const float*)d_in[8];
    const float* wih1 = (const float*)d_in[9];
    const float* whh1 = (const float*)d_in[10];
    const float* bih1 = (const float*)d_in[11];
    const float* bhh1 = (const float*)d_in[12];
    const float* wih2 = (const float*)d_in[13];
    const float* whh2 = (const float*)d_in[14];
    const float* bih2 = (const float*)d_in[15];
    const float* bhh2 = (const float*)d_in[16];
    const float* wih3 = (const float*)d_in[17];
    const float* whh3 = (const float*)d_in[18];
    const float* bih3 = (const float*)d_in[19];
    const float* bhh3 = (const float*)d_in[20];

    int N = in_sizes[0] / DH;
    int E = in_sizes[1] / 2;
    int B = (N + SCB - 1) / SCB;
    int nstripes = (N + 127) / 128;
    int nblk64 = (N + 63) / 64;
    int span = (N + 7) / 8;
    int chunkE = (E + NCHUNK - 1) / NCHUNK;

    char* wsp = (char*)d_ws;
    auto alloc = [&](size_t bytes) -> char* {
        char* p = wsp;
        wsp += (bytes + 63) & ~(size_t)63;
        return p;
    };
    unsigned* cnt = (unsigned*)alloc((size_t)N * 4);
    int* offs     = (int*)alloc(((size_t)N + 1) * 4);
    int* cur      = (int*)alloc((size_t)N * 4);
    float* dinv   = (float*)alloc((size_t)N * 4);
    unsigned* bsum= (unsigned*)alloc(((size_t)B + 1) * 4);
    int* csr_src  = (int*)alloc((size_t)E * 4);
    short* xwb    = (short*)alloc((size_t)N * DH * 2);   // pre-scaled bf16 table
    float* x2     = (float*)alloc((size_t)N * DH * 4);
    short* w1t    = (short*)alloc((size_t)DH * DH * 2);
    short* w2t    = (short*)alloc((size_t)DH * DH * 2);
    const int WN = 3 * DH * DH;      // 49152
    short* wbAll  = (short*)alloc((size_t)6 * WN * 2);
    short* wb[6];
    for (int i = 0; i < 6; i++) wb[i] = wbAll + (size_t)i * WN;

    float* out  = (float*)d_out;
    float* h1n  = out;
    float* h2n  = out + (size_t)N * DH;
    float* h3n  = out + 2 * (size_t)N * DH;

    // ---- weight prep (bf16) ----
    f2bf6_k<<<(6 * WN + 255) / 256, 256, 0, stream>>>(wih1, whh1, wih2, whh2, wih3, whh3, wbAll, WN);
    transpose_bf2_k<<<(2 * DH * DH + 255) / 256, 256, 0, stream>>>(g1w, g2w, w1t, w2t);

    // ---- CSR build (per call; deterministic), XCD-partitioned ----
    hipMemsetAsync(cnt, 0, (size_t)N * 4, stream);
    deg2_k<<<8 * NCHUNK, 256, 0, stream>>>(ei, E, cnt, span, chunkE);
    scan1_k<<<B, 256, 0, stream>>>(cnt, N, offs, bsum);
    scan2_k<<<1, 1024, 0, stream>>>(bsum, B);
    scan3_k<<<(N + 255) / 256, 256, 0, stream>>>(offs, cur, dinv, cnt, bsum, N, B);
    fill2_k<<<8 * NCHUNK, 256, 0, stream>>>(ei, E, cur, csr_src, span, chunkE);

    int gblocks = (N + 3) / 4;

    // ---- GCN layer 1 ----
    gemm_mfma_k<<<nstripes, 256, 0, stream>>>(x, w1t, dinv, xwb, N);
    gather_k<<<gblocks, 256, 0, stream>>>(csr_src, offs, dinv, (const unsigned*)xwb, g1b, x2, N);

    // ---- GCN layer 2 ----
    gemm_mfma_k<<<nstripes, 256, 0, stream>>>(x2, w2t, dinv, xwb, N);
    gather_k<<<gblocks, 256, 0, stream>>>(csr_src, offs, dinv, (const unsigned*)xwb, g2b, x2, N);

    // ---- fused GRU chain (one launch) ----
    gru3_mfma_k<<<nblk64, 512, 0, stream>>>(x2, h1, h2, h3,
                                            wb[0], wb[1], wb[2], wb[3], wb[4], wb[5],
                                            bih1, bhh1, bih2, bhh2, bih3, bhh3,
                                            h1n, h2n, h3n, N);
}